// Round 5
// baseline (1194.655 us; speedup 1.0000x reference)
//
#include <hip/hip_runtime.h>
#include <hip/hip_bf16.h>

namespace {
constexpr int B = 16, T = 500, C = 512, KW = 7, NH = 8, HD = 64, HID = 2048;
constexpr int M = B * T;             // 8000 rows
constexpr float SCALE = 0.125f;      // 1/sqrt(HD)
constexpr int BTC = B * T * C;       // 4,096,000
// weight arena segment offsets (bf16 element offsets)
constexpr int CC = C * C;                      // 262144
constexpr int SEG_PW0 = 0;
constexpr int SEG_PW1 = CC;
constexpr int SEG_WQ  = 2 * CC;
constexpr int SEG_WK  = 3 * CC;  // contiguous after WQ -> fused QKV GEMM
constexpr int SEG_WV  = 4 * CC;
constexpr int SEG_WO  = 5 * CC;
constexpr int SEG_W1  = 6 * CC;                // 1572864
constexpr int SEG_W2  = 6 * CC + HID * C;     // 2621440
constexpr int SEG_END = 6 * CC + 2 * HID * C; // 3670016
}

typedef short s16x8 __attribute__((ext_vector_type(8)));   // 8 bf16 (4 VGPRs)
typedef float f32x4v __attribute__((ext_vector_type(4)));  // MFMA acc
typedef unsigned short u16x4 __attribute__((ext_vector_type(4)));

__device__ __forceinline__ unsigned int bfrne(float f) {  // f32 -> bf16 RNE
  unsigned int u = __float_as_uint(f);
  return (u + 0x7fffu + ((u >> 16) & 1u)) >> 16;
}
__device__ __forceinline__ unsigned int pack2(float a, float b) {
  return bfrne(a) | (bfrne(b) << 16);
}

// async global->LDS DMA, 16B per lane; lds dst must be wave-uniform base
// (HW writes base + lane*16), global src is per-lane.
__device__ __forceinline__ void gl_lds16(const unsigned short* g,
                                         unsigned short* l) {
  __builtin_amdgcn_global_load_lds(
      (const __attribute__((address_space(1))) void*)g,
      (__attribute__((address_space(3))) void*)l, 16, 0, 0);
}

// -------- per-layer weight convert: 8 tensors -> bf16 arena (1 launch) ------
__global__ __launch_bounds__(256) void cvtw_kernel(
    const float* __restrict__ pw0, const float* __restrict__ pw1,
    const float* __restrict__ wqp, const float* __restrict__ wkp,
    const float* __restrict__ wvp, const float* __restrict__ wop,
    const float* __restrict__ w1p, const float* __restrict__ w2p,
    unsigned short* __restrict__ dst) {
  size_t e = ((size_t)blockIdx.x * 256 + threadIdx.x) * 8;
  const float* src;
  size_t off;
  if      (e < SEG_PW1) { src = pw0; off = e - SEG_PW0; }
  else if (e < SEG_WQ)  { src = pw1; off = e - SEG_PW1; }
  else if (e < SEG_WK)  { src = wqp; off = e - SEG_WQ; }
  else if (e < SEG_WV)  { src = wkp; off = e - SEG_WK; }
  else if (e < SEG_WO)  { src = wvp; off = e - SEG_WV; }
  else if (e < SEG_W1)  { src = wop; off = e - SEG_WO; }
  else if (e < SEG_W2)  { src = w1p; off = e - SEG_W1; }
  else                  { src = w2p; off = e - SEG_W2; }
  float4 a = *(const float4*)(src + off);
  float4 b = *(const float4*)(src + off + 4);
  uint4 o;
  o.x = pack2(a.x, a.y); o.y = pack2(a.z, a.w);
  o.z = pack2(b.x, b.y); o.w = pack2(b.z, b.w);
  *(uint4*)(dst + e) = o;
}

// -------- concat bq|bk|bv (512 each) into one 1536 bias vector --------------
__global__ __launch_bounds__(256) void biascat_kernel(
    const float* __restrict__ bq, const float* __restrict__ bk,
    const float* __restrict__ bv, float* __restrict__ dst) {
  int i = blockIdx.x * 256 + threadIdx.x;  // 0..1535
  float v = (i < 512) ? bq[i] : (i < 1024 ? bk[i - 512] : bv[i - 1024]);
  dst[i] = v;
}

// ---------------- MFMA bf16 GEMM: Y[M,N] = X[M,K] @ W[N,K]^T + bias ---------
// 128x128 tile, BK=64, 4 waves of 64x64.
// Staging: global_load_lds width=16 (8 ops/wave/tile), TRIPLE-buffered,
// depth-2 prefetch with counted s_waitcnt vmcnt(8) (two 16KB-pair tiles in
// flight per wave -> 64KB/CU outstanding; hides loaded-L3 latency).
// LDS tiles are LINEAR [128 rows][64 k] bf16 (DMA needs it); bank spread via
// chunk XOR applied identically on the GLOBAL source and the ds_read address:
// 16B chunk gc = pc ^ (row&7). Read pattern is conflict-free per 8-lane group.
// A-frag: lane holds X[m=lane&15][k=quad*8+j]; B-frag: W[n=lane&15][k=...].
// C/D: col=lane&15, row=quad*4+reg.
template <bool RELU, bool YBF>
__global__ __launch_bounds__(256) void gemm_mfma(
    const unsigned short* __restrict__ Xb,
    const unsigned short* __restrict__ Wb, const float* __restrict__ bias,
    void* __restrict__ Yv, int N, int K) {
  __shared__ unsigned short As[3][128 * 64];  // 3 x 16KB
  __shared__ unsigned short Bs[3][128 * 64];  // total 96KB
  const int tid = threadIdx.x;
  const int w = tid >> 6, lane = tid & 63;
  const int quad = lane >> 4, r15 = lane & 15;

  // XCD-aware bijective block swizzle: consecutive tiles land on one XCD ->
  // the 4..12 blocks sharing an A m-panel hit the same L2.
  const int gx = gridDim.x;
  const int nwg = gx * gridDim.y;
  const int orig = blockIdx.y * gx + blockIdx.x;
  const int q8 = nwg >> 3, r8 = nwg & 7;
  const int xcd = orig & 7, sidx = orig >> 3;
  const int tile =
      (xcd < r8 ? xcd * (q8 + 1) : r8 * (q8 + 1) + (xcd - r8) * q8) + sidx;
  const int n0 = (tile % gx) * 128;
  const int m0 = (tile / gx) * 128;

  // ---- staging map: 16 DMA instrs per tile (4/wave per matrix) ----
  // instr idx=w*4+j covers LDS bytes [idx*1KB, +1KB) = phys rows idx*8..+8;
  // lane l lands at row idx*8+(l>>3), phys chunk l&7; global chunk =
  // (l&7)^(l>>3)  (XOR swizzle; row&7 == l>>3 since idx*8 is 8-aligned).
  const int lrow = lane >> 3;                  // 0..7
  const int gch8 = ((lane & 7) ^ lrow) * 8;    // element offset of 16B chunk
  size_t xsrc[4], wsrc[4];
#pragma unroll
  for (int j = 0; j < 4; ++j) {
    int rr = w * 32 + j * 8 + lrow;
    xsrc[j] = (size_t)min(m0 + rr, M - 1) * K + gch8;
    wsrc[j] = (size_t)(n0 + rr) * K + gch8;
  }

  auto issue = [&](int buf, int k0) {
#pragma unroll
    for (int j = 0; j < 4; ++j)
      gl_lds16(Xb + xsrc[j] + k0, &As[buf][(w * 4 + j) * 512]);
#pragma unroll
    for (int j = 0; j < 4; ++j)
      gl_lds16(Wb + wsrc[j] + k0, &Bs[buf][(w * 4 + j) * 512]);
  };

  // ---- fragment read offsets (same XOR involution on the read side) ----
  const int mh = (w & 1) * 64, nh = (w >> 1) * 64;
  const int c0 = (quad ^ (r15 & 7)) * 8;        // k-chunk for kk=0
  const int c1 = ((quad ^ (r15 & 7)) ^ 4) * 8;  // k-chunk for kk=1 (+32 elems)

  f32x4v acc[4][4];
#pragma unroll
  for (int i = 0; i < 4; ++i)
#pragma unroll
    for (int j = 0; j < 4; ++j) acc[i][j] = {0.f, 0.f, 0.f, 0.f};

  const int nk = K / 64;
  issue(0, 0);
  issue(1, 64);
  int cur = 0, nxt = 2;
  for (int c = 0; c < nk; ++c) {
    // tile c (8 oldest ops/wave) must be done; tile c+1's 8 ops stay in flight
    if (c + 1 < nk)
      asm volatile("s_waitcnt vmcnt(8)" ::: "memory");
    else
      asm volatile("s_waitcnt vmcnt(0)" ::: "memory");
    __builtin_amdgcn_s_barrier();
    __builtin_amdgcn_sched_barrier(0);
    if (c + 2 < nk) issue(nxt, (c + 2) * 64);
    const unsigned short* Ac = As[cur];
    const unsigned short* Bc = Bs[cur];
    s16x8 a0[4], a1[4], b0[4], b1[4];
#pragma unroll
    for (int im = 0; im < 4; ++im) {
      int base = (mh + im * 16 + r15) * 64;
      a0[im] = *(const s16x8*)&Ac[base + c0];
      a1[im] = *(const s16x8*)&Ac[base + c1];
    }
#pragma unroll
    for (int in = 0; in < 4; ++in) {
      int base = (nh + in * 16 + r15) * 64;
      b0[in] = *(const s16x8*)&Bc[base + c0];
      b1[in] = *(const s16x8*)&Bc[base + c1];
    }
#pragma unroll
    for (int in = 0; in < 4; ++in)
#pragma unroll
      for (int im = 0; im < 4; ++im) {
        acc[im][in] = __builtin_amdgcn_mfma_f32_16x16x32_bf16(
            a0[im], b0[in], acc[im][in], 0, 0, 0);
        acc[im][in] = __builtin_amdgcn_mfma_f32_16x16x32_bf16(
            a1[im], b1[in], acc[im][in], 0, 0, 0);
      }
    cur = (cur == 2) ? 0 : cur + 1;
    nxt = (nxt == 2) ? 0 : nxt + 1;
  }
  // epilogue
#pragma unroll
  for (int in = 0; in < 4; ++in) {
    int col = n0 + nh + in * 16 + r15;
    float bv = bias[col];
#pragma unroll
    for (int im = 0; im < 4; ++im) {
      int rowb = m0 + mh + im * 16 + quad * 4;
#pragma unroll
      for (int r = 0; r < 4; ++r) {
        int row = rowb + r;
        if (row < M) {
          float v = acc[im][in][r] + bv;
          if (RELU) v = fmaxf(v, 0.f);
          if (YBF)
            ((unsigned short*)Yv)[(size_t)row * N + col] =
                (unsigned short)bfrne(v);
          else
            ((float*)Yv)[(size_t)row * N + col] = v;
        }
      }
    }
  }
}

// ------- depthwise conv (K=7, pad 3) along T, (B,T,C), bf16 out, 2 ch/thread
__global__ __launch_bounds__(256) void dwconv_kernel(
    const float* __restrict__ X, const float* __restrict__ W,
    const float* __restrict__ bias, unsigned short* __restrict__ Y) {
  int gid = blockIdx.x * 256 + threadIdx.x;  // 0 .. T*C/2-1
  int b = blockIdx.y;
  int e = gid * 2;
  int t = e >> 9;
  int c = e & 511;  // even
  float acc0 = bias[c], acc1 = bias[c + 1];
  size_t base = (size_t)b * T * C;
#pragma unroll
  for (int k = 0; k < KW; ++k) {
    int tt = t + k - 3;
    if (tt >= 0 && tt < T) {
      float2 xv = *(const float2*)&X[base + (size_t)tt * C + c];
      acc0 += xv.x * W[c * KW + k];
      acc1 += xv.y * W[(c + 1) * KW + k];
    }
  }
  *(unsigned int*)&Y[base + e] = pack2(acc0, acc1);
}

// --------- row LayerNorm over C=512, one wave/row, vectorized, opt bf16 out -
template <bool DUAL>
__global__ __launch_bounds__(256) void ln_kernel(
    const float* __restrict__ X, const float* __restrict__ g,
    const float* __restrict__ bta, float* __restrict__ Y,
    unsigned short* __restrict__ Yb) {
  int row = blockIdx.x * 4 + (threadIdx.x >> 6);
  int lane = threadIdx.x & 63;
  const float* x = X + (size_t)row * C + lane * 8;
  float4 a = *(const float4*)x;
  float4 b2 = *(const float4*)(x + 4);
  float v[8] = {a.x, a.y, a.z, a.w, b2.x, b2.y, b2.z, b2.w};
  float s = 0.f, ss = 0.f;
#pragma unroll
  for (int i = 0; i < 8; ++i) {
    s += v[i];
    ss += v[i] * v[i];
  }
#pragma unroll
  for (int off = 32; off; off >>= 1) {
    s += __shfl_xor(s, off);
    ss += __shfl_xor(ss, off);
  }
  float mean = s * (1.f / C);
  float var = ss * (1.f / C) - mean * mean;
  var = fmaxf(var, 0.f);
  float rstd = rsqrtf(var + 1e-5f);
  float4 g0 = *(const float4*)(g + lane * 8);
  float4 g1 = *(const float4*)(g + lane * 8 + 4);
  float4 be0 = *(const float4*)(bta + lane * 8);
  float4 be1 = *(const float4*)(bta + lane * 8 + 4);
  float gg[8] = {g0.x, g0.y, g0.z, g0.w, g1.x, g1.y, g1.z, g1.w};
  float bb[8] = {be0.x, be0.y, be0.z, be0.w, be1.x, be1.y, be1.z, be1.w};
  float o[8];
#pragma unroll
  for (int i = 0; i < 8; ++i) o[i] = (v[i] - mean) * rstd * gg[i] + bb[i];
  float* y = Y + (size_t)row * C + lane * 8;
  float4 w0 = {o[0], o[1], o[2], o[3]};
  float4 w1 = {o[4], o[5], o[6], o[7]};
  *(float4*)y = w0;
  *(float4*)(y + 4) = w1;
  if (DUAL) {
    uint4 ob;
    ob.x = pack2(o[0], o[1]); ob.y = pack2(o[2], o[3]);
    ob.z = pack2(o[4], o[5]); ob.w = pack2(o[6], o[7]);
    *(uint4*)(Yb + (size_t)row * C + lane * 8) = ob;
  }
}

// ---------- causal flash attention, MFMA bf16, bf16 in (QKV fused) / out ----
// QKV: [M, 1536] bf16 (Q|K|V each 512 cols). Block = (64-q tile, head, batch);
// 4 waves, wave w owns q rows [q0+16w, q0+16w+16). Key tiles of 64.
// S = Q @ K^T via mfma_16x16x32_bf16 (K staged [key][d] in LDS, SCALE applied
// post-MFMA); online softmax in f32 (16-lane shfl reductions); P -> bf16 via
// per-wave LDS round-trip; PV MFMA against V staged transposed [d][key].
__global__ __launch_bounds__(256) void attn_mfma_kernel(
    const unsigned short* __restrict__ QKV, unsigned short* __restrict__ Yb) {
  constexpr int QS = 3 * C;  // 1536
  constexpr int LDK = 72;    // pad breaks 128B-stride bank alignment
  __shared__ __align__(16) unsigned short Ks[64 * LDK];     // [key][d]
  __shared__ __align__(16) unsigned short Vt[64 * LDK];     // [d][key]
  __shared__ __align__(16) unsigned short Ps[4][16 * LDK];  // per-wave [q][key]
  const int tid = threadIdx.x;
  const int lane = tid & 63, w = tid >> 6;
  const int quad = lane >> 4, r15 = lane & 15;
  const int qt = blockIdx.x, hh = blockIdx.y, b = blockIdx.z;
  const int q0 = qt * 64;
  const size_t hbase = (size_t)hh * HD;

  // Q A-frags: lane holds Q[q0+16w+r15][ks*32+quad*8 .. +8)
  s16x8 qa[2];
  {
    int qr = min(q0 + w * 16 + r15, T - 1);
    const unsigned short* qp = QKV + ((size_t)b * T + qr) * QS + hbase;
#pragma unroll
    for (int ks = 0; ks < 2; ++ks)
      qa[ks] = *(const s16x8*)(qp + ks * 32 + quad * 8);
  }

  f32x4v oacc[4];
  float mm[4], ll[4];
#pragma unroll
  for (int i = 0; i < 4; ++i) {
    oacc[i] = {0.f, 0.f, 0.f, 0.f};
    mm[i] = -1e30f;
    ll[i] = 0.f;
  }

  // staging maps
  const int krow = tid >> 2, kd = (tid & 3) * 16;        // K: 16 shorts/thread
  const int vk4 = (tid >> 4) * 4, vd4 = (tid & 15) * 4;  // V: 4x4 transpose

  const int kend = min(q0 + 63, T - 1);
  for (int key0 = 0; key0 <= kend; key0 += 64) {
    __syncthreads();
    // ---- stage K tile [key][d] (bf16 copy) ----
    {
      int key = key0 + krow;
      if (key < T) {
        const unsigned short* kp =
            QKV + ((size_t)b * T + key) * QS + C + hbase + kd;
        uint4 k0 = *(const uint4*)kp;
        uint4 k1 = *(const uint4*)(kp + 8);
        *(uint4*)&Ks[krow * LDK + kd] = k0;
        *(uint4*)&Ks[krow * LDK + kd + 8] = k1;
      } else {
        uint4 z = {0u, 0u, 0u, 0u};
        *(uint4*)&Ks[krow * LDK + kd] = z;
        *(uint4*)&Ks[krow * LDK + kd + 8] = z;
      }
    }
    // ---- stage V tile transposed [d][key] ----
    {
      u16x4 va[4];
#pragma unroll
      for (int j = 0; j < 4; ++j) {
        int key = key0 + vk4 + j;
        if (key < T) {
          va[j] = *(const u16x4*)(QKV + ((size_t)b * T + key) * QS + 2 * C +
                                  hbase + vd4);
        } else {
          va[j] = (u16x4){0, 0, 0, 0};
        }
      }
#pragma unroll
      for (int i = 0; i < 4; ++i) {
        uint2 o2;
        o2.x = (unsigned int)va[0][i] | ((unsigned int)va[1][i] << 16);
        o2.y = (unsigned int)va[2][i] | ((unsigned int)va[3][i] << 16);
        *(uint2*)&Vt[(vd4 + i) * LDK + vk4] = o2;
      }
    }
    __syncthreads();

    // ---- S = Q K^T (per wave: 16 q x 64 keys) ----
    f32x4v sa[4];
#pragma unroll
    for (int nt = 0; nt < 4; ++nt) {
      s16x8 kb0 = *(const s16x8*)&Ks[(nt * 16 + r15) * LDK + quad * 8];
      s16x8 kb1 = *(const s16x8*)&Ks[(nt * 16 + r15) * LDK + 32 + quad * 8];
      f32x4v z = {0.f, 0.f, 0.f, 0.f};
      z = __builtin_amdgcn_mfma_f32_16x16x32_bf16(qa[0], kb0, z, 0, 0, 0);
      z = __builtin_amdgcn_mfma_f32_16x16x32_bf16(qa[1], kb1, z, 0, 0, 0);
      sa[nt] = z;
    }
    const bool diag = (key0 == q0);  // only the diagonal tile needs masking

    // ---- online softmax; C-layout row = quad*4+r, col = nt*16+r15 ----
#pragma unroll
    for (int r = 0; r < 4; ++r) {
      int q = q0 + w * 16 + quad * 4 + r;
      float sv[4];
#pragma unroll
      for (int nt = 0; nt < 4; ++nt) {
        sv[nt] = sa[nt][r] * SCALE;
        if (diag && (key0 + nt * 16 + r15 > q)) sv[nt] = -1e30f;
      }
      float mx = fmaxf(fmaxf(sv[0], sv[1]), fmaxf(sv[2], sv[3]));
      mx = fmaxf(mx, __shfl_xor(mx, 8));
      mx = fmaxf(mx, __shfl_xor(mx, 4));
      mx = fmaxf(mx, __shfl_xor(mx, 2));
      mx = fmaxf(mx, __shfl_xor(mx, 1));
      float mnew = fmaxf(mm[r], mx);
      float alpha = __expf(mm[r] - mnew);
      float ps = 0.f;
#pragma unroll
      for (int nt = 0; nt < 4; ++nt) {
        float p = __expf(sv[nt] - mnew);
        ps += p;
        Ps[w][(quad * 4 + r) * LDK + nt * 16 + r15] =
            (unsigned short)bfrne(p);
      }
      ps += __shfl_xor(ps, 8);
      ps += __shfl_xor(ps, 4);
      ps += __shfl_xor(ps, 2);
      ps += __shfl_xor(ps, 1);
      ll[r] = ll[r] * alpha + ps;
      mm[r] = mnew;
#pragma unroll
      for (int dt = 0; dt < 4; ++dt) oacc[dt][r] *= alpha;
    }
    // per-wave LDS round-trip: drain this wave's Ps writes before reading
    asm volatile("s_waitcnt lgkmcnt(0)" ::: "memory");
    __builtin_amdgcn_sched_barrier(0);

    // ---- O += P @ V ----
    s16x8 pa0 = *(const s16x8*)&Ps[w][r15 * LDK + quad * 8];
    s16x8 pa1 = *(const s16x8*)&Ps[w][r15 * LDK + 32 + quad * 8];
#pragma unroll
    for (int dt = 0; dt < 4; ++dt) {
      s16x8 vb0 = *(const s16x8*)&Vt[(dt * 16 + r15) * LDK + quad * 8];
      s16x8 vb1 = *(const s16x8*)&Vt[(dt * 16 + r15) * LDK + 32 + quad * 8];
      oacc[dt] =
          __builtin_amdgcn_mfma_f32_16x16x32_bf16(pa0, vb0, oacc[dt], 0, 0, 0);
      oacc[dt] =
          __builtin_amdgcn_mfma_f32_16x16x32_bf16(pa1, vb1, oacc[dt], 0, 0, 0);
    }
  }

  // ---- write out bf16 (row = quad*4+r, col = dt*16+r15) ----
#pragma unroll
  for (int r = 0; r < 4; ++r) {
    int q = q0 + w * 16 + quad * 4 + r;
    if (q < T) {
      float inv = 1.f / ll[r];
      unsigned short* yp = Yb + ((size_t)b * T + q) * C + hbase;
#pragma unroll
      for (int dt = 0; dt < 4; ++dt)
        yp[dt * 16 + r15] = (unsigned short)bfrne(oacc[dt][r] * inv);
    }
  }
}

extern "C" void kernel_launch(void* const* d_in, const int* in_sizes, int n_in,
                              void* d_out, int out_size, void* d_ws,
                              size_t ws_size, hipStream_t stream) {
  const float* x     = (const float*)d_in[0];
  const float* dw_w  = (const float*)d_in[1];
  const float* dw_b  = (const float*)d_in[2];
  const float* pw_w  = (const float*)d_in[3];
  const float* pw_b  = (const float*)d_in[4];
  const float* cln_g = (const float*)d_in[5];
  const float* cln_b = (const float*)d_in[6];
  const float* wq    = (const float*)d_in[7];
  const float* bq    = (const float*)d_in[8];
  const float* wk    = (const float*)d_in[9];
  const float* bk    = (const float*)d_in[10];
  const float* wv    = (const float*)d_in[11];
  const float* bv    = (const float*)d_in[12];
  const float* wo    = (const float*)d_in[13];
  const float* bo    = (const float*)d_in[14];
  const float* aln_g = (const float*)d_in[15];
  const float* aln_b = (const float*)d_in[16];
  const float* w1    = (const float*)d_in[17];
  const float* b1    = (const float*)d_in[18];
  const float* w2    = (const float*)d_in[19];
  const float* b2    = (const float*)d_in[20];
  const float* fln_g = (const float*)d_in[21];
  const float* fln_b = (const float*)d_in[22];

  float* ws = (float*)d_ws;
  float* A  = ws;                      // bias concat + ffn1-out (bf16 spans A,Bf)
  float* Bf = ws + (size_t)BTC;        // bf16 activation slot
  float* R0 = ws + (size_t)2 * BTC;    // QKV bf16 (spans into R1) / f32 outs
  float* R1 = ws + (size_t)3 * BTC;    // O-proj f32 out
  float* R2 = ws + (size_t)4 * BTC;    // ffn1 input bf16
  unsigned short* WA = (unsigned short*)(ws + (size_t)5 * BTC);  // 7.4 MB
  float* out = (float*)d_out;          // 3 layer outputs, f32

  unsigned short* xbf   = (unsigned short*)Bf;   // conv-GEMM in / QKV in / attn out
  unsigned short* qkvbf = (unsigned short*)R0;   // QKV GEMM out [M,1536] bf16
  unsigned short* fbf   = (unsigned short*)R2;   // ffn1 input bf16
  unsigned short* hbf   = (unsigned short*)A;    // ffn1 output bf16 (spans A,Bf)
  float* qkvb = A;                               // 1536-wide concat bias

  dim3 blk(256);
  dim3 gemmC(C / 128, 63);        // N=512
  dim3 gemmQKV(3 * C / 128, 63);  // N=1536
  dim3 gemmH(HID / 128, 63);      // N=2048
  dim3 convG(T * C / 512, B);     // 2 channels/thread
  dim3 attnG((T + 63) / 64, NH, B);
  int cvtwB = SEG_END / 2048;     // 1792 blocks

  for (int l = 0; l < 3; ++l) {
    float* h = out + (size_t)l * BTC;
    const float* hin = (l == 0) ? x : out + (size_t)(l - 1) * BTC;
    cvtw_kernel<<<cvtwB, blk, 0, stream>>>(
        pw_w + (size_t)(2 * l) * CC, pw_w + (size_t)(2 * l + 1) * CC,
        wq + (size_t)l * CC, wk + (size_t)l * CC, wv + (size_t)l * CC,
        wo + (size_t)l * CC, w1 + (size_t)l * HID * C,
        w2 + (size_t)l * C * HID, WA);
    biascat_kernel<<<6, blk, 0, stream>>>(bq + (size_t)l * C,
                                          bk + (size_t)l * C,
                                          bv + (size_t)l * C, qkvb);
    // ---- 2 conv blocks ----
    for (int cb = 0; cb < 2; ++cb) {
      int lc = l * 2 + cb;
      const float* src = (cb == 0) ? hin : h;
      dwconv_kernel<<<convG, blk, 0, stream>>>(src, dw_w + (size_t)lc * C * KW,
                                               dw_b + (size_t)lc * C, xbf);
      gemm_mfma<false, false><<<gemmC, blk, 0, stream>>>(
          xbf, WA + (cb ? SEG_PW1 : SEG_PW0), pw_b + (size_t)lc * C, R0, C, C);
      if (cb == 0)
        ln_kernel<false><<<M / 4, blk, 0, stream>>>(
            R0, cln_g + (size_t)lc * C, cln_b + (size_t)lc * C, h, nullptr);
      else  // dual: bf16 copy feeds fused QKV GEMM
        ln_kernel<true><<<M / 4, blk, 0, stream>>>(
            R0, cln_g + (size_t)lc * C, cln_b + (size_t)lc * C, h, xbf);
    }
    // ---- attention ----
    gemm_mfma<false, true><<<gemmQKV, blk, 0, stream>>>(
        xbf, WA + SEG_WQ, qkvb, qkvbf, 3 * C, C);
    attn_mfma_kernel<<<attnG, blk, 0, stream>>>(qkvbf, xbf);
    gemm_mfma<false, false><<<gemmC, blk, 0, stream>>>(
        xbf, WA + SEG_WO, bo + (size_t)l * C, R1, C, C);
    ln_kernel<true><<<M / 4, blk, 0, stream>>>(
        R1, aln_g + (size_t)l * C, aln_b + (size_t)l * C, h, fbf);
    // ---- FFN ----
    gemm_mfma<true, true><<<gemmH, blk, 0, stream>>>(
        fbf, WA + SEG_W1, b1 + (size_t)l * HID, hbf, HID, C);
    gemm_mfma<false, false><<<gemmC, blk, 0, stream>>>(
        hbf, WA + SEG_W2, b2 + (size_t)l * C, R0, C, HID);
    ln_kernel<false><<<M / 4, blk, 0, stream>>>(
        R0, fln_g + (size_t)l * C, fln_b + (size_t)l * C, h, nullptr);
  }
}

// Round 6
// 1046.104 us; speedup vs baseline: 1.1420x; 1.1420x over previous
//
#include <hip/hip_runtime.h>
#include <hip/hip_bf16.h>

namespace {
constexpr int B = 16, T = 500, C = 512, KW = 7, NH = 8, HD = 64, HID = 2048;
constexpr int M = B * T;             // 8000 rows
constexpr float SCALE = 0.125f;      // 1/sqrt(HD)
constexpr int BTC = B * T * C;       // 4,096,000
// weight arena segment offsets (bf16 element offsets)
constexpr int CC = C * C;                      // 262144
constexpr int SEG_PW0 = 0;
constexpr int SEG_PW1 = CC;
constexpr int SEG_WQ  = 2 * CC;
constexpr int SEG_WK  = 3 * CC;  // contiguous after WQ -> fused QKV GEMM
constexpr int SEG_WV  = 4 * CC;
constexpr int SEG_WO  = 5 * CC;
constexpr int SEG_W1  = 6 * CC;                // 1572864
constexpr int SEG_W2  = 6 * CC + HID * C;     // 2621440
constexpr int SEG_END = 6 * CC + 2 * HID * C; // 3670016
}

typedef short s16x8 __attribute__((ext_vector_type(8)));   // 8 bf16 (4 VGPRs)
typedef float f32x4v __attribute__((ext_vector_type(4)));  // MFMA acc
typedef unsigned short u16x4 __attribute__((ext_vector_type(4)));

__device__ __forceinline__ unsigned int bfrne(float f) {  // f32 -> bf16 RNE
  unsigned int u = __float_as_uint(f);
  return (u + 0x7fffu + ((u >> 16) & 1u)) >> 16;
}
__device__ __forceinline__ unsigned int pack2(float a, float b) {
  return bfrne(a) | (bfrne(b) << 16);
}

// async global->LDS DMA, 16B per lane; lds dst must be wave-uniform base
// (HW writes base + lane*16), global src is per-lane.
__device__ __forceinline__ void gl_lds16(const unsigned short* g,
                                         unsigned short* l) {
  __builtin_amdgcn_global_load_lds(
      (const __attribute__((address_space(1))) void*)g,
      (__attribute__((address_space(3))) void*)l, 16, 0, 0);
}

// -------- per-layer weight convert: 8 tensors -> bf16 arena (1 launch) ------
__global__ __launch_bounds__(256) void cvtw_kernel(
    const float* __restrict__ pw0, const float* __restrict__ pw1,
    const float* __restrict__ wqp, const float* __restrict__ wkp,
    const float* __restrict__ wvp, const float* __restrict__ wop,
    const float* __restrict__ w1p, const float* __restrict__ w2p,
    unsigned short* __restrict__ dst) {
  size_t e = ((size_t)blockIdx.x * 256 + threadIdx.x) * 8;
  const float* src;
  size_t off;
  if      (e < SEG_PW1) { src = pw0; off = e - SEG_PW0; }
  else if (e < SEG_WQ)  { src = pw1; off = e - SEG_PW1; }
  else if (e < SEG_WK)  { src = wqp; off = e - SEG_WQ; }
  else if (e < SEG_WV)  { src = wkp; off = e - SEG_WK; }
  else if (e < SEG_WO)  { src = wvp; off = e - SEG_WV; }
  else if (e < SEG_W1)  { src = wop; off = e - SEG_WO; }
  else if (e < SEG_W2)  { src = w1p; off = e - SEG_W1; }
  else                  { src = w2p; off = e - SEG_W2; }
  float4 a = *(const float4*)(src + off);
  float4 b = *(const float4*)(src + off + 4);
  uint4 o;
  o.x = pack2(a.x, a.y); o.y = pack2(a.z, a.w);
  o.z = pack2(b.x, b.y); o.w = pack2(b.z, b.w);
  *(uint4*)(dst + e) = o;
}

// -------- concat bq|bk|bv (512 each) into one 1536 bias vector --------------
__global__ __launch_bounds__(256) void biascat_kernel(
    const float* __restrict__ bq, const float* __restrict__ bk,
    const float* __restrict__ bv, float* __restrict__ dst) {
  int i = blockIdx.x * 256 + threadIdx.x;  // 0..1535
  float v = (i < 512) ? bq[i] : (i < 1024 ? bk[i - 512] : bv[i - 1024]);
  dst[i] = v;
}

// ---------------- MFMA bf16 GEMM: Y[M,N] = X[M,K] @ W[N,K]^T + bias ---------
// 128x128 tile, BK=32, 8 WAVES (512 thr) of 32x64 each -> 8 waves/CU even on
// grid-limited launches (252 blocks), doubling latency-hiding TLP vs 4 waves.
// Staging: global_load_lds width=16, 2 ops/wave/tile, TRIPLE-buffered (48KB),
// depth-2 prefetch, counted s_waitcnt vmcnt(2) (next tile stays in flight).
// LDS tiles LINEAR [128][32] bf16 (DMA requires); k-chunk XOR swizzle applied
// identically on the GLOBAL source and the ds_read offset (both-sides rule):
// phys chunk = logical chunk ^ (row&3). Read is conflict-free (R3: 0 cnt).
// A-frag: lane holds X[m=lane&15][k=quad*8+j]; B-frag: W[n=lane&15][k=...].
// C/D: col=lane&15, row=quad*4+reg.
template <bool RELU, bool YBF>
__global__ __launch_bounds__(512) void gemm_mfma(
    const unsigned short* __restrict__ Xb,
    const unsigned short* __restrict__ Wb, const float* __restrict__ bias,
    void* __restrict__ Yv, int N, int K) {
  __shared__ unsigned short As[3][128 * 32];  // 3 x 8KB
  __shared__ unsigned short Bs[3][128 * 32];  // total 48KB
  const int tid = threadIdx.x;
  const int w = tid >> 6, lane = tid & 63;
  const int quad = lane >> 4, r15 = lane & 15;

  // XCD-aware bijective block swizzle: consecutive tiles land on one XCD ->
  // blocks sharing an A m-panel hit the same L2.
  const int gx = gridDim.x;
  const int nwg = gx * gridDim.y;
  const int orig = blockIdx.y * gx + blockIdx.x;
  const int q8 = nwg >> 3, r8 = nwg & 7;
  const int xcd = orig & 7, sidx = orig >> 3;
  const int tile =
      (xcd < r8 ? xcd * (q8 + 1) : r8 * (q8 + 1) + (xcd - r8) * q8) + sidx;
  const int n0 = (tile % gx) * 128;
  const int m0 = (tile / gx) * 128;

  // ---- staging map: 16 DMA ops per tile (1 A-op + 1 B-op per wave) ----
  // wave w's op covers LDS [w*1KB, +1KB) = rows w*16..+16 (32 elems/row);
  // lane l -> row w*16+(l>>2), phys chunk l&3; global (logical) chunk =
  // (l&3) ^ (row&3) = (l&3)^((l>>2)&3)  (XOR involution).
  const int srow = lane >> 2;                        // 0..15
  const int gch = ((lane & 3) ^ (srow & 3)) * 8;     // elem offset of 16B chunk
  const size_t xsrc = (size_t)min(m0 + w * 16 + srow, M - 1) * K + gch;
  const size_t wsrc = (size_t)(n0 + w * 16 + srow) * K + gch;

  auto issue = [&](int buf, int k0) {
    gl_lds16(Xb + xsrc + k0, &As[buf][w * 512]);
    gl_lds16(Wb + wsrc + k0, &Bs[buf][w * 512]);
  };

  // ---- fragment read offsets (same XOR involution on the read side) ----
  const int wm = w >> 1, wn = w & 1;     // 4 x 2 wave grid
  const int mh = wm * 32, nh = wn * 64;  // wave sub-tile 32M x 64N
  const int c0 = (quad ^ (r15 & 3)) * 8;

  f32x4v acc[2][4];
#pragma unroll
  for (int i = 0; i < 2; ++i)
#pragma unroll
    for (int j = 0; j < 4; ++j) acc[i][j] = {0.f, 0.f, 0.f, 0.f};

  const int nk = K / 32;
  issue(0, 0);
  issue(1, 32);
  int cur = 0, nxt = 2;
  for (int c = 0; c < nk; ++c) {
    // tile c (2 oldest ops/wave) done; tile c+1's 2 ops stay in flight
    if (c + 1 < nk)
      asm volatile("s_waitcnt vmcnt(2)" ::: "memory");
    else
      asm volatile("s_waitcnt vmcnt(0)" ::: "memory");
    __builtin_amdgcn_s_barrier();
    __builtin_amdgcn_sched_barrier(0);
    if (c + 2 < nk) issue(nxt, (c + 2) * 32);
    const unsigned short* Ac = As[cur];
    const unsigned short* Bc = Bs[cur];
    s16x8 af[2], bg[4];
#pragma unroll
    for (int im = 0; im < 2; ++im)
      af[im] = *(const s16x8*)&Ac[(mh + im * 16 + r15) * 32 + c0];
#pragma unroll
    for (int in = 0; in < 4; ++in)
      bg[in] = *(const s16x8*)&Bc[(nh + in * 16 + r15) * 32 + c0];
#pragma unroll
    for (int in = 0; in < 4; ++in)
#pragma unroll
      for (int im = 0; im < 2; ++im)
        acc[im][in] = __builtin_amdgcn_mfma_f32_16x16x32_bf16(
            af[im], bg[in], acc[im][in], 0, 0, 0);
    cur = (cur == 2) ? 0 : cur + 1;
    nxt = (nxt == 2) ? 0 : nxt + 1;
  }
  // epilogue
#pragma unroll
  for (int in = 0; in < 4; ++in) {
    int col = n0 + nh + in * 16 + r15;
    float bv = bias[col];
#pragma unroll
    for (int im = 0; im < 2; ++im) {
      int rowb = m0 + mh + im * 16 + quad * 4;
#pragma unroll
      for (int r = 0; r < 4; ++r) {
        int row = rowb + r;
        if (row < M) {
          float v = acc[im][in][r] + bv;
          if (RELU) v = fmaxf(v, 0.f);
          if (YBF)
            ((unsigned short*)Yv)[(size_t)row * N + col] =
                (unsigned short)bfrne(v);
          else
            ((float*)Yv)[(size_t)row * N + col] = v;
        }
      }
    }
  }
}

// ------- depthwise conv (K=7, pad 3) along T, (B,T,C), bf16 out, 2 ch/thread
__global__ __launch_bounds__(256) void dwconv_kernel(
    const float* __restrict__ X, const float* __restrict__ W,
    const float* __restrict__ bias, unsigned short* __restrict__ Y) {
  int gid = blockIdx.x * 256 + threadIdx.x;  // 0 .. T*C/2-1
  int b = blockIdx.y;
  int e = gid * 2;
  int t = e >> 9;
  int c = e & 511;  // even
  float acc0 = bias[c], acc1 = bias[c + 1];
  size_t base = (size_t)b * T * C;
#pragma unroll
  for (int k = 0; k < KW; ++k) {
    int tt = t + k - 3;
    if (tt >= 0 && tt < T) {
      float2 xv = *(const float2*)&X[base + (size_t)tt * C + c];
      acc0 += xv.x * W[c * KW + k];
      acc1 += xv.y * W[(c + 1) * KW + k];
    }
  }
  *(unsigned int*)&Y[base + e] = pack2(acc0, acc1);
}

// --------- row LayerNorm over C=512, one wave/row, vectorized, opt bf16 out -
template <bool DUAL>
__global__ __launch_bounds__(256) void ln_kernel(
    const float* __restrict__ X, const float* __restrict__ g,
    const float* __restrict__ bta, float* __restrict__ Y,
    unsigned short* __restrict__ Yb) {
  int row = blockIdx.x * 4 + (threadIdx.x >> 6);
  int lane = threadIdx.x & 63;
  const float* x = X + (size_t)row * C + lane * 8;
  float4 a = *(const float4*)x;
  float4 b2 = *(const float4*)(x + 4);
  float v[8] = {a.x, a.y, a.z, a.w, b2.x, b2.y, b2.z, b2.w};
  float s = 0.f, ss = 0.f;
#pragma unroll
  for (int i = 0; i < 8; ++i) {
    s += v[i];
    ss += v[i] * v[i];
  }
#pragma unroll
  for (int off = 32; off; off >>= 1) {
    s += __shfl_xor(s, off);
    ss += __shfl_xor(ss, off);
  }
  float mean = s * (1.f / C);
  float var = ss * (1.f / C) - mean * mean;
  var = fmaxf(var, 0.f);
  float rstd = rsqrtf(var + 1e-5f);
  float4 g0 = *(const float4*)(g + lane * 8);
  float4 g1 = *(const float4*)(g + lane * 8 + 4);
  float4 be0 = *(const float4*)(bta + lane * 8);
  float4 be1 = *(const float4*)(bta + lane * 8 + 4);
  float gg[8] = {g0.x, g0.y, g0.z, g0.w, g1.x, g1.y, g1.z, g1.w};
  float bb[8] = {be0.x, be0.y, be0.z, be0.w, be1.x, be1.y, be1.z, be1.w};
  float o[8];
#pragma unroll
  for (int i = 0; i < 8; ++i) o[i] = (v[i] - mean) * rstd * gg[i] + bb[i];
  float* y = Y + (size_t)row * C + lane * 8;
  float4 w0 = {o[0], o[1], o[2], o[3]};
  float4 w1 = {o[4], o[5], o[6], o[7]};
  *(float4*)y = w0;
  *(float4*)(y + 4) = w1;
  if (DUAL) {
    uint4 ob;
    ob.x = pack2(o[0], o[1]); ob.y = pack2(o[2], o[3]);
    ob.z = pack2(o[4], o[5]); ob.w = pack2(o[6], o[7]);
    *(uint4*)(Yb + (size_t)row * C + lane * 8) = ob;
  }
}

// ---------- causal flash attention, MFMA bf16, bf16 in (QKV fused) / out ----
// QKV: [M, 1536] bf16 (Q|K|V each 512 cols). Block = (64-q tile, head, batch);
// 4 waves, wave w owns q rows [q0+16w, q0+16w+16). Key tiles of 64.
// S = Q @ K^T via mfma_16x16x32_bf16 (K staged [key][d] in LDS, SCALE applied
// post-MFMA); online softmax in f32 (16-lane shfl reductions); P -> bf16 via
// per-wave LDS round-trip; PV MFMA against V staged transposed [d][key].
__global__ __launch_bounds__(256) void attn_mfma_kernel(
    const unsigned short* __restrict__ QKV, unsigned short* __restrict__ Yb) {
  constexpr int QS = 3 * C;  // 1536
  constexpr int LDK = 72;    // pad breaks 128B-stride bank alignment
  __shared__ __align__(16) unsigned short Ks[64 * LDK];     // [key][d]
  __shared__ __align__(16) unsigned short Vt[64 * LDK];     // [d][key]
  __shared__ __align__(16) unsigned short Ps[4][16 * LDK];  // per-wave [q][key]
  const int tid = threadIdx.x;
  const int lane = tid & 63, w = tid >> 6;
  const int quad = lane >> 4, r15 = lane & 15;
  const int qt = blockIdx.x, hh = blockIdx.y, b = blockIdx.z;
  const int q0 = qt * 64;
  const size_t hbase = (size_t)hh * HD;

  // Q A-frags: lane holds Q[q0+16w+r15][ks*32+quad*8 .. +8)
  s16x8 qa[2];
  {
    int qr = min(q0 + w * 16 + r15, T - 1);
    const unsigned short* qp = QKV + ((size_t)b * T + qr) * QS + hbase;
#pragma unroll
    for (int ks = 0; ks < 2; ++ks)
      qa[ks] = *(const s16x8*)(qp + ks * 32 + quad * 8);
  }

  f32x4v oacc[4];
  float mm[4], ll[4];
#pragma unroll
  for (int i = 0; i < 4; ++i) {
    oacc[i] = {0.f, 0.f, 0.f, 0.f};
    mm[i] = -1e30f;
    ll[i] = 0.f;
  }

  // staging maps
  const int krow = tid >> 2, kd = (tid & 3) * 16;        // K: 16 shorts/thread
  const int vk4 = (tid >> 4) * 4, vd4 = (tid & 15) * 4;  // V: 4x4 transpose

  const int kend = min(q0 + 63, T - 1);
  for (int key0 = 0; key0 <= kend; key0 += 64) {
    __syncthreads();
    // ---- stage K tile [key][d] (bf16 copy) ----
    {
      int key = key0 + krow;
      if (key < T) {
        const unsigned short* kp =
            QKV + ((size_t)b * T + key) * QS + C + hbase + kd;
        uint4 k0 = *(const uint4*)kp;
        uint4 k1 = *(const uint4*)(kp + 8);
        *(uint4*)&Ks[krow * LDK + kd] = k0;
        *(uint4*)&Ks[krow * LDK + kd + 8] = k1;
      } else {
        uint4 z = {0u, 0u, 0u, 0u};
        *(uint4*)&Ks[krow * LDK + kd] = z;
        *(uint4*)&Ks[krow * LDK + kd + 8] = z;
      }
    }
    // ---- stage V tile transposed [d][key] ----
    {
      u16x4 va[4];
#pragma unroll
      for (int j = 0; j < 4; ++j) {
        int key = key0 + vk4 + j;
        if (key < T) {
          va[j] = *(const u16x4*)(QKV + ((size_t)b * T + key) * QS + 2 * C +
                                  hbase + vd4);
        } else {
          va[j] = (u16x4){0, 0, 0, 0};
        }
      }
#pragma unroll
      for (int i = 0; i < 4; ++i) {
        uint2 o2;
        o2.x = (unsigned int)va[0][i] | ((unsigned int)va[1][i] << 16);
        o2.y = (unsigned int)va[2][i] | ((unsigned int)va[3][i] << 16);
        *(uint2*)&Vt[(vd4 + i) * LDK + vk4] = o2;
      }
    }
    __syncthreads();

    // ---- S = Q K^T (per wave: 16 q x 64 keys) ----
    f32x4v sa[4];
#pragma unroll
    for (int nt = 0; nt < 4; ++nt) {
      s16x8 kb0 = *(const s16x8*)&Ks[(nt * 16 + r15) * LDK + quad * 8];
      s16x8 kb1 = *(const s16x8*)&Ks[(nt * 16 + r15) * LDK + 32 + quad * 8];
      f32x4v z = {0.f, 0.f, 0.f, 0.f};
      z = __builtin_amdgcn_mfma_f32_16x16x32_bf16(qa[0], kb0, z, 0, 0, 0);
      z = __builtin_amdgcn_mfma_f32_16x16x32_bf16(qa[1], kb1, z, 0, 0, 0);
      sa[nt] = z;
    }
    const bool diag = (key0 == q0);  // only the diagonal tile needs masking

    // ---- online softmax; C-layout row = quad*4+r, col = nt*16+r15 ----
#pragma unroll
    for (int r = 0; r < 4; ++r) {
      int q = q0 + w * 16 + quad * 4 + r;
      float sv[4];
#pragma unroll
      for (int nt = 0; nt < 4; ++nt) {
        sv[nt] = sa[nt][r] * SCALE;
        if (diag && (key0 + nt * 16 + r15 > q)) sv[nt] = -1e30f;
      }
      float mx = fmaxf(fmaxf(sv[0], sv[1]), fmaxf(sv[2], sv[3]));
      mx = fmaxf(mx, __shfl_xor(mx, 8));
      mx = fmaxf(mx, __shfl_xor(mx, 4));
      mx = fmaxf(mx, __shfl_xor(mx, 2));
      mx = fmaxf(mx, __shfl_xor(mx, 1));
      float mnew = fmaxf(mm[r], mx);
      float alpha = __expf(mm[r] - mnew);
      float ps = 0.f;
#pragma unroll
      for (int nt = 0; nt < 4; ++nt) {
        float p = __expf(sv[nt] - mnew);
        ps += p;
        Ps[w][(quad * 4 + r) * LDK + nt * 16 + r15] =
            (unsigned short)bfrne(p);
      }
      ps += __shfl_xor(ps, 8);
      ps += __shfl_xor(ps, 4);
      ps += __shfl_xor(ps, 2);
      ps += __shfl_xor(ps, 1);
      ll[r] = ll[r] * alpha + ps;
      mm[r] = mnew;
#pragma unroll
      for (int dt = 0; dt < 4; ++dt) oacc[dt][r] *= alpha;
    }
    // per-wave LDS round-trip: drain this wave's Ps writes before reading
    asm volatile("s_waitcnt lgkmcnt(0)" ::: "memory");
    __builtin_amdgcn_sched_barrier(0);

    // ---- O += P @ V ----
    s16x8 pa0 = *(const s16x8*)&Ps[w][r15 * LDK + quad * 8];
    s16x8 pa1 = *(const s16x8*)&Ps[w][r15 * LDK + 32 + quad * 8];
#pragma unroll
    for (int dt = 0; dt < 4; ++dt) {
      s16x8 vb0 = *(const s16x8*)&Vt[(dt * 16 + r15) * LDK + quad * 8];
      s16x8 vb1 = *(const s16x8*)&Vt[(dt * 16 + r15) * LDK + 32 + quad * 8];
      oacc[dt] =
          __builtin_amdgcn_mfma_f32_16x16x32_bf16(pa0, vb0, oacc[dt], 0, 0, 0);
      oacc[dt] =
          __builtin_amdgcn_mfma_f32_16x16x32_bf16(pa1, vb1, oacc[dt], 0, 0, 0);
    }
  }

  // ---- write out bf16 (row = quad*4+r, col = dt*16+r15) ----
#pragma unroll
  for (int r = 0; r < 4; ++r) {
    int q = q0 + w * 16 + quad * 4 + r;
    if (q < T) {
      float inv = 1.f / ll[r];
      unsigned short* yp = Yb + ((size_t)b * T + q) * C + hbase;
#pragma unroll
      for (int dt = 0; dt < 4; ++dt)
        yp[dt * 16 + r15] = (unsigned short)bfrne(oacc[dt][r] * inv);
    }
  }
}

extern "C" void kernel_launch(void* const* d_in, const int* in_sizes, int n_in,
                              void* d_out, int out_size, void* d_ws,
                              size_t ws_size, hipStream_t stream) {
  const float* x     = (const float*)d_in[0];
  const float* dw_w  = (const float*)d_in[1];
  const float* dw_b  = (const float*)d_in[2];
  const float* pw_w  = (const float*)d_in[3];
  const float* pw_b  = (const float*)d_in[4];
  const float* cln_g = (const float*)d_in[5];
  const float* cln_b = (const float*)d_in[6];
  const float* wq    = (const float*)d_in[7];
  const float* bq    = (const float*)d_in[8];
  const float* wk    = (const float*)d_in[9];
  const float* bk    = (const float*)d_in[10];
  const float* wv    = (const float*)d_in[11];
  const float* bv    = (const float*)d_in[12];
  const float* wo    = (const float*)d_in[13];
  const float* bo    = (const float*)d_in[14];
  const float* aln_g = (const float*)d_in[15];
  const float* aln_b = (const float*)d_in[16];
  const float* w1    = (const float*)d_in[17];
  const float* b1    = (const float*)d_in[18];
  const float* w2    = (const float*)d_in[19];
  const float* b2    = (const float*)d_in[20];
  const float* fln_g = (const float*)d_in[21];
  const float* fln_b = (const float*)d_in[22];

  float* ws = (float*)d_ws;
  float* A  = ws;                      // bias concat + ffn1-out (bf16 spans A,Bf)
  float* Bf = ws + (size_t)BTC;        // bf16 activation slot
  float* R0 = ws + (size_t)2 * BTC;    // QKV bf16 (spans into R1) / f32 outs
  float* R1 = ws + (size_t)3 * BTC;    // O-proj f32 out
  float* R2 = ws + (size_t)4 * BTC;    // ffn1 input bf16
  unsigned short* WA = (unsigned short*)(ws + (size_t)5 * BTC);  // 7.4 MB
  float* out = (float*)d_out;          // 3 layer outputs, f32

  unsigned short* xbf   = (unsigned short*)Bf;   // conv-GEMM in / QKV in / attn out
  unsigned short* qkvbf = (unsigned short*)R0;   // QKV GEMM out [M,1536] bf16
  unsigned short* fbf   = (unsigned short*)R2;   // ffn1 input bf16
  unsigned short* hbf   = (unsigned short*)A;    // ffn1 output bf16 (spans A,Bf)
  float* qkvb = A;                               // 1536-wide concat bias

  dim3 blk(256);
  dim3 blkG(512);                 // 8-wave GEMM blocks
  dim3 gemmC(C / 128, 63);        // N=512
  dim3 gemmQKV(3 * C / 128, 63);  // N=1536
  dim3 gemmH(HID / 128, 63);      // N=2048
  dim3 convG(T * C / 512, B);     // 2 channels/thread
  dim3 attnG((T + 63) / 64, NH, B);
  int cvtwB = SEG_END / 2048;     // 1792 blocks

  for (int l = 0; l < 3; ++l) {
    float* h = out + (size_t)l * BTC;
    const float* hin = (l == 0) ? x : out + (size_t)(l - 1) * BTC;
    cvtw_kernel<<<cvtwB, blk, 0, stream>>>(
        pw_w + (size_t)(2 * l) * CC, pw_w + (size_t)(2 * l + 1) * CC,
        wq + (size_t)l * CC, wk + (size_t)l * CC, wv + (size_t)l * CC,
        wo + (size_t)l * CC, w1 + (size_t)l * HID * C,
        w2 + (size_t)l * C * HID, WA);
    biascat_kernel<<<6, blk, 0, stream>>>(bq + (size_t)l * C,
                                          bk + (size_t)l * C,
                                          bv + (size_t)l * C, qkvb);
    // ---- 2 conv blocks ----
    for (int cb = 0; cb < 2; ++cb) {
      int lc = l * 2 + cb;
      const float* src = (cb == 0) ? hin : h;
      dwconv_kernel<<<convG, blk, 0, stream>>>(src, dw_w + (size_t)lc * C * KW,
                                               dw_b + (size_t)lc * C, xbf);
      gemm_mfma<false, false><<<gemmC, blkG, 0, stream>>>(
          xbf, WA + (cb ? SEG_PW1 : SEG_PW0), pw_b + (size_t)lc * C, R0, C, C);
      if (cb == 0)
        ln_kernel<false><<<M / 4, blk, 0, stream>>>(
            R0, cln_g + (size_t)lc * C, cln_b + (size_t)lc * C, h, nullptr);
      else  // dual: bf16 copy feeds fused QKV GEMM
        ln_kernel<true><<<M / 4, blk, 0, stream>>>(
            R0, cln_g + (size_t)lc * C, cln_b + (size_t)lc * C, h, xbf);
    }
    // ---- attention ----
    gemm_mfma<false, true><<<gemmQKV, blkG, 0, stream>>>(
        xbf, WA + SEG_WQ, qkvb, qkvbf, 3 * C, C);
    attn_mfma_kernel<<<attnG, blk, 0, stream>>>(qkvbf, xbf);
    gemm_mfma<false, false><<<gemmC, blkG, 0, stream>>>(
        xbf, WA + SEG_WO, bo + (size_t)l * C, R1, C, C);
    ln_kernel<true><<<M / 4, blk, 0, stream>>>(
        R1, aln_g + (size_t)l * C, aln_b + (size_t)l * C, h, fbf);
    // ---- FFN ----
    gemm_mfma<true, true><<<gemmH, blkG, 0, stream>>>(
        fbf, WA + SEG_W1, b1 + (size_t)l * HID, hbf, HID, C);
    gemm_mfma<false, false><<<gemmC, blkG, 0, stream>>>(
        hbf, WA + SEG_W2, b2 + (size_t)l * C, R0, C, HID);
    ln_kernel<false><<<M / 4, blk, 0, stream>>>(
        R0, fln_g + (size_t)l * C, fln_b + (size_t)l * C, h, nullptr);
  }
}

// Round 7
// 977.593 us; speedup vs baseline: 1.2220x; 1.0701x over previous
//
#include <hip/hip_runtime.h>
#include <hip/hip_bf16.h>

namespace {
constexpr int B = 16, T = 500, C = 512, KW = 7, NH = 8, HD = 64, HID = 2048;
constexpr int M = B * T;             // 8000 rows
constexpr float SCALE = 0.125f;      // 1/sqrt(HD)
constexpr int BTC = B * T * C;       // 4,096,000
// weight arena segment offsets (bf16 element offsets)
constexpr int CC = C * C;                      // 262144
constexpr int SEG_PW0 = 0;
constexpr int SEG_PW1 = CC;
constexpr int SEG_WQ  = 2 * CC;
constexpr int SEG_WK  = 3 * CC;  // contiguous after WQ -> fused QKV GEMM
constexpr int SEG_WV  = 4 * CC;
constexpr int SEG_WO  = 5 * CC;
constexpr int SEG_W1  = 6 * CC;                // 1572864
constexpr int SEG_W2  = 6 * CC + HID * C;     // 2621440
constexpr int SEG_END = 6 * CC + 2 * HID * C; // 3670016
}

typedef short s16x8 __attribute__((ext_vector_type(8)));   // 8 bf16 (4 VGPRs)
typedef float f32x4v __attribute__((ext_vector_type(4)));  // MFMA acc
typedef unsigned short u16x4 __attribute__((ext_vector_type(4)));

__device__ __forceinline__ unsigned int bfrne(float f) {  // f32 -> bf16 RNE
  unsigned int u = __float_as_uint(f);
  return (u + 0x7fffu + ((u >> 16) & 1u)) >> 16;
}
__device__ __forceinline__ unsigned int pack2(float a, float b) {
  return bfrne(a) | (bfrne(b) << 16);
}

// async global->LDS DMA, 16B per lane; lds dst must be wave-uniform base
// (HW writes base + lane*16), global src is per-lane.
__device__ __forceinline__ void gl_lds16(const unsigned short* g,
                                         unsigned short* l) {
  __builtin_amdgcn_global_load_lds(
      (const __attribute__((address_space(1))) void*)g,
      (__attribute__((address_space(3))) void*)l, 16, 0, 0);
}

// -------- per-layer weight convert: 8 tensors -> bf16 arena (1 launch) ------
__global__ __launch_bounds__(256) void cvtw_kernel(
    const float* __restrict__ pw0, const float* __restrict__ pw1,
    const float* __restrict__ wqp, const float* __restrict__ wkp,
    const float* __restrict__ wvp, const float* __restrict__ wop,
    const float* __restrict__ w1p, const float* __restrict__ w2p,
    unsigned short* __restrict__ dst) {
  size_t e = ((size_t)blockIdx.x * 256 + threadIdx.x) * 8;
  const float* src;
  size_t off;
  if      (e < SEG_PW1) { src = pw0; off = e - SEG_PW0; }
  else if (e < SEG_WQ)  { src = pw1; off = e - SEG_PW1; }
  else if (e < SEG_WK)  { src = wqp; off = e - SEG_WQ; }
  else if (e < SEG_WV)  { src = wkp; off = e - SEG_WK; }
  else if (e < SEG_WO)  { src = wvp; off = e - SEG_WV; }
  else if (e < SEG_W1)  { src = wop; off = e - SEG_WO; }
  else if (e < SEG_W2)  { src = w1p; off = e - SEG_W1; }
  else                  { src = w2p; off = e - SEG_W2; }
  float4 a = *(const float4*)(src + off);
  float4 b = *(const float4*)(src + off + 4);
  uint4 o;
  o.x = pack2(a.x, a.y); o.y = pack2(a.z, a.w);
  o.z = pack2(b.x, b.y); o.w = pack2(b.z, b.w);
  *(uint4*)(dst + e) = o;
}

// -------- concat bq|bk|bv (512 each) into one 1536 bias vector --------------
__global__ __launch_bounds__(256) void biascat_kernel(
    const float* __restrict__ bq, const float* __restrict__ bk,
    const float* __restrict__ bv, float* __restrict__ dst) {
  int i = blockIdx.x * 256 + threadIdx.x;  // 0..1535
  float v = (i < 512) ? bq[i] : (i < 1024 ? bk[i - 512] : bv[i - 1024]);
  dst[i] = v;
}

// ---------------- MFMA bf16 GEMM: Y[M,N] = X[M,K] @ W[N,K]^T + bias ---------
// 128x128 tile, BK=32, 8 waves (512 thr) of 32x64 each.
// SPLIT: gridDim.z=2, block ks handles K-half [ks*K/2,(ks+1)*K/2), writes f32
// partial to Yv + ks*M*N; the following LayerNorm sums both partials (free
// reduction). Doubles blocks/CU on the 252-block N=512 launches AND halves
// the serial K chain -> latency-bound time ~halves.
// Staging: global_load_lds width=16, 2 ops/wave/tile, triple-buffered (48KB),
// depth-2 prefetch, counted s_waitcnt vmcnt(2).
// LDS LINEAR [128][32] bf16 (DMA requires); 16B-chunk XOR swizzle applied
// identically on the GLOBAL source and the ds_read offset (both-sides rule):
// phys chunk = logical chunk ^ ((row>>1)&3). Within each 16-lane quad the
// reads cover all 8 bank-groups x2 -> 2-way (free). (R6's (row&3) variant
// covered only 4 groups -> measured 3.1M conflicts.)
// A-frag: lane holds X[m=lane&15][k=quad*8+j]; B-frag: W[n=lane&15][k=...].
// C/D: col=lane&15, row=quad*4+reg.
template <bool RELU, bool YBF, bool SPLIT>
__global__ __launch_bounds__(512) void gemm_mfma(
    const unsigned short* __restrict__ Xb,
    const unsigned short* __restrict__ Wb, const float* __restrict__ bias,
    void* __restrict__ Yv, int N, int K) {
  __shared__ unsigned short As[3][128 * 32];  // 3 x 8KB
  __shared__ unsigned short Bs[3][128 * 32];  // total 48KB
  const int tid = threadIdx.x;
  const int w = tid >> 6, lane = tid & 63;
  const int quad = lane >> 4, r15 = lane & 15;

  const int ks = SPLIT ? blockIdx.z : 0;
  const int K2 = SPLIT ? (K >> 1) : K;
  const int kbase = ks * K2;

  // XCD-aware bijective block swizzle (locality heuristic over x,y only).
  const int gx = gridDim.x;
  const int nwg = gx * gridDim.y;
  const int orig = blockIdx.y * gx + blockIdx.x;
  const int q8 = nwg >> 3, r8 = nwg & 7;
  const int xcd = orig & 7, sidx = orig >> 3;
  const int tile =
      (xcd < r8 ? xcd * (q8 + 1) : r8 * (q8 + 1) + (xcd - r8) * q8) + sidx;
  const int n0 = (tile % gx) * 128;
  const int m0 = (tile / gx) * 128;

  // ---- staging map: 16 DMA ops per tile (1 A-op + 1 B-op per wave) ----
  // wave w's op covers LDS rows w*16..+16; lane l -> row w*16+(l>>2),
  // phys chunk l&3; logical (global) chunk = (l&3) ^ ((l>>3)&3)
  // (since (row>>1)&3 == (l>>3)&3 for 16-aligned wave bases).
  const int srow = lane >> 2;                          // 0..15
  const int gch = ((lane & 3) ^ ((lane >> 3) & 3)) * 8;  // 16B chunk offset
  const size_t xsrc =
      (size_t)min(m0 + w * 16 + srow, M - 1) * K + kbase + gch;
  const size_t wsrc = (size_t)(n0 + w * 16 + srow) * K + kbase + gch;

  auto issue = [&](int buf, int k0) {
    gl_lds16(Xb + xsrc + k0, &As[buf][w * 512]);
    gl_lds16(Wb + wsrc + k0, &Bs[buf][w * 512]);
  };

  // ---- fragment read offsets (same XOR involution on the read side) ----
  const int wm = w >> 1, wn = w & 1;     // 4 x 2 wave grid
  const int mh = wm * 32, nh = wn * 64;  // wave sub-tile 32M x 64N
  const int c0 = (quad ^ ((r15 >> 1) & 3)) * 8;

  f32x4v acc[2][4];
#pragma unroll
  for (int i = 0; i < 2; ++i)
#pragma unroll
    for (int j = 0; j < 4; ++j) acc[i][j] = {0.f, 0.f, 0.f, 0.f};

  const int nk = K2 / 32;
  issue(0, 0);
  issue(1, 32);
  int cur = 0, nxt = 2;
  for (int c = 0; c < nk; ++c) {
    // tile c (2 oldest ops/wave) done; tile c+1's 2 ops stay in flight
    if (c + 1 < nk)
      asm volatile("s_waitcnt vmcnt(2)" ::: "memory");
    else
      asm volatile("s_waitcnt vmcnt(0)" ::: "memory");
    __builtin_amdgcn_s_barrier();
    __builtin_amdgcn_sched_barrier(0);
    if (c + 2 < nk) issue(nxt, (c + 2) * 32);
    const unsigned short* Ac = As[cur];
    const unsigned short* Bc = Bs[cur];
    s16x8 af[2], bg[4];
#pragma unroll
    for (int im = 0; im < 2; ++im)
      af[im] = *(const s16x8*)&Ac[(mh + im * 16 + r15) * 32 + c0];
#pragma unroll
    for (int in = 0; in < 4; ++in)
      bg[in] = *(const s16x8*)&Bc[(nh + in * 16 + r15) * 32 + c0];
#pragma unroll
    for (int in = 0; in < 4; ++in)
#pragma unroll
      for (int im = 0; im < 2; ++im)
        acc[im][in] = __builtin_amdgcn_mfma_f32_16x16x32_bf16(
            af[im], bg[in], acc[im][in], 0, 0, 0);
    cur = (cur == 2) ? 0 : cur + 1;
    nxt = (nxt == 2) ? 0 : nxt + 1;
  }
  // epilogue
  float* Yf = (float*)Yv + (SPLIT ? (size_t)ks * M * N : 0);
#pragma unroll
  for (int in = 0; in < 4; ++in) {
    int col = n0 + nh + in * 16 + r15;
    float bv = bias[col];
    if (SPLIT && ks) bv = 0.f;  // bias added once (ks=0 partial)
#pragma unroll
    for (int im = 0; im < 2; ++im) {
      int rowb = m0 + mh + im * 16 + quad * 4;
#pragma unroll
      for (int r = 0; r < 4; ++r) {
        int row = rowb + r;
        if (row < M) {
          float v = acc[im][in][r] + bv;
          if (RELU) v = fmaxf(v, 0.f);
          if (YBF)
            ((unsigned short*)Yv)[(size_t)row * N + col] =
                (unsigned short)bfrne(v);
          else
            Yf[(size_t)row * N + col] = v;
        }
      }
    }
  }
}

// ------- depthwise conv (K=7, pad 3) along T, (B,T,C), bf16 out, 2 ch/thread
__global__ __launch_bounds__(256) void dwconv_kernel(
    const float* __restrict__ X, const float* __restrict__ W,
    const float* __restrict__ bias, unsigned short* __restrict__ Y) {
  int gid = blockIdx.x * 256 + threadIdx.x;  // 0 .. T*C/2-1
  int b = blockIdx.y;
  int e = gid * 2;
  int t = e >> 9;
  int c = e & 511;  // even
  float acc0 = bias[c], acc1 = bias[c + 1];
  size_t base = (size_t)b * T * C;
#pragma unroll
  for (int k = 0; k < KW; ++k) {
    int tt = t + k - 3;
    if (tt >= 0 && tt < T) {
      float2 xv = *(const float2*)&X[base + (size_t)tt * C + c];
      acc0 += xv.x * W[c * KW + k];
      acc1 += xv.y * W[(c + 1) * KW + k];
    }
  }
  *(unsigned int*)&Y[base + e] = pack2(acc0, acc1);
}

// --------- row LayerNorm over C=512, one wave/row, vectorized --------------
// SUM2: input = X[row] + X[row + BTC] (sums the two split-K GEMM partials --
// the free reduction). DUAL: also emit bf16 copy.
template <bool DUAL, bool SUM2>
__global__ __launch_bounds__(256) void ln_kernel(
    const float* __restrict__ X, const float* __restrict__ g,
    const float* __restrict__ bta, float* __restrict__ Y,
    unsigned short* __restrict__ Yb) {
  int row = blockIdx.x * 4 + (threadIdx.x >> 6);
  int lane = threadIdx.x & 63;
  const float* x = X + (size_t)row * C + lane * 8;
  float4 a = *(const float4*)x;
  float4 b2 = *(const float4*)(x + 4);
  float v[8] = {a.x, a.y, a.z, a.w, b2.x, b2.y, b2.z, b2.w};
  if (SUM2) {
    const float* x2 = x + (size_t)BTC;
    float4 a2 = *(const float4*)x2;
    float4 b3 = *(const float4*)(x2 + 4);
    v[0] += a2.x; v[1] += a2.y; v[2] += a2.z; v[3] += a2.w;
    v[4] += b3.x; v[5] += b3.y; v[6] += b3.z; v[7] += b3.w;
  }
  float s = 0.f, ss = 0.f;
#pragma unroll
  for (int i = 0; i < 8; ++i) {
    s += v[i];
    ss += v[i] * v[i];
  }
#pragma unroll
  for (int off = 32; off; off >>= 1) {
    s += __shfl_xor(s, off);
    ss += __shfl_xor(ss, off);
  }
  float mean = s * (1.f / C);
  float var = ss * (1.f / C) - mean * mean;
  var = fmaxf(var, 0.f);
  float rstd = rsqrtf(var + 1e-5f);
  float4 g0 = *(const float4*)(g + lane * 8);
  float4 g1 = *(const float4*)(g + lane * 8 + 4);
  float4 be0 = *(const float4*)(bta + lane * 8);
  float4 be1 = *(const float4*)(bta + lane * 8 + 4);
  float gg[8] = {g0.x, g0.y, g0.z, g0.w, g1.x, g1.y, g1.z, g1.w};
  float bb[8] = {be0.x, be0.y, be0.z, be0.w, be1.x, be1.y, be1.z, be1.w};
  float o[8];
#pragma unroll
  for (int i = 0; i < 8; ++i) o[i] = (v[i] - mean) * rstd * gg[i] + bb[i];
  float* y = Y + (size_t)row * C + lane * 8;
  float4 w0 = {o[0], o[1], o[2], o[3]};
  float4 w1 = {o[4], o[5], o[6], o[7]};
  *(float4*)y = w0;
  *(float4*)(y + 4) = w1;
  if (DUAL) {
    uint4 ob;
    ob.x = pack2(o[0], o[1]); ob.y = pack2(o[2], o[3]);
    ob.z = pack2(o[4], o[5]); ob.w = pack2(o[6], o[7]);
    *(uint4*)(Yb + (size_t)row * C + lane * 8) = ob;
  }
}

// ---------- causal flash attention, MFMA bf16, bf16 in (QKV fused) / out ----
// QKV: [M, 1536] bf16 (Q|K|V each 512 cols). Block = (64-q tile, head, batch);
// 4 waves, wave w owns q rows [q0+16w, q0+16w+16). Key tiles of 64.
// S = Q @ K^T via mfma_16x16x32_bf16 (K staged [key][d] in LDS, SCALE applied
// post-MFMA); online softmax in f32 (16-lane shfl reductions); P -> bf16 via
// per-wave LDS round-trip; PV MFMA against V staged transposed [d][key].
__global__ __launch_bounds__(256) void attn_mfma_kernel(
    const unsigned short* __restrict__ QKV, unsigned short* __restrict__ Yb) {
  constexpr int QS = 3 * C;  // 1536
  constexpr int LDK = 72;    // pad breaks 128B-stride bank alignment
  __shared__ __align__(16) unsigned short Ks[64 * LDK];     // [key][d]
  __shared__ __align__(16) unsigned short Vt[64 * LDK];     // [d][key]
  __shared__ __align__(16) unsigned short Ps[4][16 * LDK];  // per-wave [q][key]
  const int tid = threadIdx.x;
  const int lane = tid & 63, w = tid >> 6;
  const int quad = lane >> 4, r15 = lane & 15;
  const int qt = blockIdx.x, hh = blockIdx.y, b = blockIdx.z;
  const int q0 = qt * 64;
  const size_t hbase = (size_t)hh * HD;

  // Q A-frags: lane holds Q[q0+16w+r15][ks*32+quad*8 .. +8)
  s16x8 qa[2];
  {
    int qr = min(q0 + w * 16 + r15, T - 1);
    const unsigned short* qp = QKV + ((size_t)b * T + qr) * QS + hbase;
#pragma unroll
    for (int ks = 0; ks < 2; ++ks)
      qa[ks] = *(const s16x8*)(qp + ks * 32 + quad * 8);
  }

  f32x4v oacc[4];
  float mm[4], ll[4];
#pragma unroll
  for (int i = 0; i < 4; ++i) {
    oacc[i] = {0.f, 0.f, 0.f, 0.f};
    mm[i] = -1e30f;
    ll[i] = 0.f;
  }

  // staging maps
  const int krow = tid >> 2, kd = (tid & 3) * 16;        // K: 16 shorts/thread
  const int vk4 = (tid >> 4) * 4, vd4 = (tid & 15) * 4;  // V: 4x4 transpose

  const int kend = min(q0 + 63, T - 1);
  for (int key0 = 0; key0 <= kend; key0 += 64) {
    __syncthreads();
    // ---- stage K tile [key][d] (bf16 copy) ----
    {
      int key = key0 + krow;
      if (key < T) {
        const unsigned short* kp =
            QKV + ((size_t)b * T + key) * QS + C + hbase + kd;
        uint4 k0 = *(const uint4*)kp;
        uint4 k1 = *(const uint4*)(kp + 8);
        *(uint4*)&Ks[krow * LDK + kd] = k0;
        *(uint4*)&Ks[krow * LDK + kd + 8] = k1;
      } else {
        uint4 z = {0u, 0u, 0u, 0u};
        *(uint4*)&Ks[krow * LDK + kd] = z;
        *(uint4*)&Ks[krow * LDK + kd + 8] = z;
      }
    }
    // ---- stage V tile transposed [d][key] ----
    {
      u16x4 va[4];
#pragma unroll
      for (int j = 0; j < 4; ++j) {
        int key = key0 + vk4 + j;
        if (key < T) {
          va[j] = *(const u16x4*)(QKV + ((size_t)b * T + key) * QS + 2 * C +
                                  hbase + vd4);
        } else {
          va[j] = (u16x4){0, 0, 0, 0};
        }
      }
#pragma unroll
      for (int i = 0; i < 4; ++i) {
        uint2 o2;
        o2.x = (unsigned int)va[0][i] | ((unsigned int)va[1][i] << 16);
        o2.y = (unsigned int)va[2][i] | ((unsigned int)va[3][i] << 16);
        *(uint2*)&Vt[(vd4 + i) * LDK + vk4] = o2;
      }
    }
    __syncthreads();

    // ---- S = Q K^T (per wave: 16 q x 64 keys) ----
    f32x4v sa[4];
#pragma unroll
    for (int nt = 0; nt < 4; ++nt) {
      s16x8 kb0 = *(const s16x8*)&Ks[(nt * 16 + r15) * LDK + quad * 8];
      s16x8 kb1 = *(const s16x8*)&Ks[(nt * 16 + r15) * LDK + 32 + quad * 8];
      f32x4v z = {0.f, 0.f, 0.f, 0.f};
      z = __builtin_amdgcn_mfma_f32_16x16x32_bf16(qa[0], kb0, z, 0, 0, 0);
      z = __builtin_amdgcn_mfma_f32_16x16x32_bf16(qa[1], kb1, z, 0, 0, 0);
      sa[nt] = z;
    }
    const bool diag = (key0 == q0);  // only the diagonal tile needs masking

    // ---- online softmax; C-layout row = quad*4+r, col = nt*16+r15 ----
#pragma unroll
    for (int r = 0; r < 4; ++r) {
      int q = q0 + w * 16 + quad * 4 + r;
      float sv[4];
#pragma unroll
      for (int nt = 0; nt < 4; ++nt) {
        sv[nt] = sa[nt][r] * SCALE;
        if (diag && (key0 + nt * 16 + r15 > q)) sv[nt] = -1e30f;
      }
      float mx = fmaxf(fmaxf(sv[0], sv[1]), fmaxf(sv[2], sv[3]));
      mx = fmaxf(mx, __shfl_xor(mx, 8));
      mx = fmaxf(mx, __shfl_xor(mx, 4));
      mx = fmaxf(mx, __shfl_xor(mx, 2));
      mx = fmaxf(mx, __shfl_xor(mx, 1));
      float mnew = fmaxf(mm[r], mx);
      float alpha = __expf(mm[r] - mnew);
      float ps = 0.f;
#pragma unroll
      for (int nt = 0; nt < 4; ++nt) {
        float p = __expf(sv[nt] - mnew);
        ps += p;
        Ps[w][(quad * 4 + r) * LDK + nt * 16 + r15] =
            (unsigned short)bfrne(p);
      }
      ps += __shfl_xor(ps, 8);
      ps += __shfl_xor(ps, 4);
      ps += __shfl_xor(ps, 2);
      ps += __shfl_xor(ps, 1);
      ll[r] = ll[r] * alpha + ps;
      mm[r] = mnew;
#pragma unroll
      for (int dt = 0; dt < 4; ++dt) oacc[dt][r] *= alpha;
    }
    // per-wave LDS round-trip: drain this wave's Ps writes before reading
    asm volatile("s_waitcnt lgkmcnt(0)" ::: "memory");
    __builtin_amdgcn_sched_barrier(0);

    // ---- O += P @ V ----
    s16x8 pa0 = *(const s16x8*)&Ps[w][r15 * LDK + quad * 8];
    s16x8 pa1 = *(const s16x8*)&Ps[w][r15 * LDK + 32 + quad * 8];
#pragma unroll
    for (int dt = 0; dt < 4; ++dt) {
      s16x8 vb0 = *(const s16x8*)&Vt[(dt * 16 + r15) * LDK + quad * 8];
      s16x8 vb1 = *(const s16x8*)&Vt[(dt * 16 + r15) * LDK + 32 + quad * 8];
      oacc[dt] =
          __builtin_amdgcn_mfma_f32_16x16x32_bf16(pa0, vb0, oacc[dt], 0, 0, 0);
      oacc[dt] =
          __builtin_amdgcn_mfma_f32_16x16x32_bf16(pa1, vb1, oacc[dt], 0, 0, 0);
    }
  }

  // ---- write out bf16 (row = quad*4+r, col = dt*16+r15) ----
#pragma unroll
  for (int r = 0; r < 4; ++r) {
    int q = q0 + w * 16 + quad * 4 + r;
    if (q < T) {
      float inv = 1.f / ll[r];
      unsigned short* yp = Yb + ((size_t)b * T + q) * C + hbase;
#pragma unroll
      for (int dt = 0; dt < 4; ++dt)
        yp[dt * 16 + r15] = (unsigned short)bfrne(oacc[dt][r] * inv);
    }
  }
}

extern "C" void kernel_launch(void* const* d_in, const int* in_sizes, int n_in,
                              void* d_out, int out_size, void* d_ws,
                              size_t ws_size, hipStream_t stream) {
  const float* x     = (const float*)d_in[0];
  const float* dw_w  = (const float*)d_in[1];
  const float* dw_b  = (const float*)d_in[2];
  const float* pw_w  = (const float*)d_in[3];
  const float* pw_b  = (const float*)d_in[4];
  const float* cln_g = (const float*)d_in[5];
  const float* cln_b = (const float*)d_in[6];
  const float* wq    = (const float*)d_in[7];
  const float* bq    = (const float*)d_in[8];
  const float* wk    = (const float*)d_in[9];
  const float* bk    = (const float*)d_in[10];
  const float* wv    = (const float*)d_in[11];
  const float* bv    = (const float*)d_in[12];
  const float* wo    = (const float*)d_in[13];
  const float* bo    = (const float*)d_in[14];
  const float* aln_g = (const float*)d_in[15];
  const float* aln_b = (const float*)d_in[16];
  const float* w1    = (const float*)d_in[17];
  const float* b1    = (const float*)d_in[18];
  const float* w2    = (const float*)d_in[19];
  const float* b2    = (const float*)d_in[20];
  const float* fln_g = (const float*)d_in[21];
  const float* fln_b = (const float*)d_in[22];

  float* ws = (float*)d_ws;
  float* A  = ws;                      // qkv bias / ffn1-out bf16 (spans A,Bf)
  float* Bf = ws + (size_t)BTC;        // bf16 activation slot
  float* R0 = ws + (size_t)2 * BTC;    // partial0 / QKV bf16 (spans into R1)
  float* R1 = ws + (size_t)3 * BTC;    // partial1
  float* R2 = ws + (size_t)4 * BTC;    // ffn1 input bf16
  unsigned short* WA = (unsigned short*)(ws + (size_t)5 * BTC);  // 7.4 MB
  float* out = (float*)d_out;          // 3 layer outputs, f32

  unsigned short* xbf   = (unsigned short*)Bf;   // conv-GEMM in / QKV in / attn out
  unsigned short* qkvbf = (unsigned short*)R0;   // QKV GEMM out [M,1536] bf16
  unsigned short* fbf   = (unsigned short*)R2;   // ffn1 input bf16
  unsigned short* hbf   = (unsigned short*)A;    // ffn1 output bf16 (spans A,Bf)
  float* qkvb = A;                               // 1536-wide concat bias

  dim3 blk(256);
  dim3 blkG(512);                    // 8-wave GEMM blocks
  dim3 gemmC2(C / 128, 63, 2);       // N=512, split-K=2 -> 504 blocks
  dim3 gemmQKV(3 * C / 128, 63);     // N=1536, 756 blocks
  dim3 gemmH(HID / 128, 63);         // N=2048, 1008 blocks
  dim3 convG(T * C / 512, B);        // 2 channels/thread
  dim3 attnG((T + 63) / 64, NH, B);
  int cvtwB = SEG_END / 2048;        // 1792 blocks

  for (int l = 0; l < 3; ++l) {
    float* h = out + (size_t)l * BTC;
    const float* hin = (l == 0) ? x : out + (size_t)(l - 1) * BTC;
    cvtw_kernel<<<cvtwB, blk, 0, stream>>>(
        pw_w + (size_t)(2 * l) * CC, pw_w + (size_t)(2 * l + 1) * CC,
        wq + (size_t)l * CC, wk + (size_t)l * CC, wv + (size_t)l * CC,
        wo + (size_t)l * CC, w1 + (size_t)l * HID * C,
        w2 + (size_t)l * C * HID, WA);
    biascat_kernel<<<6, blk, 0, stream>>>(bq + (size_t)l * C,
                                          bk + (size_t)l * C,
                                          bv + (size_t)l * C, qkvb);
    // ---- 2 conv blocks (pointwise GEMM split-K=2, LN sums partials) ----
    for (int cb = 0; cb < 2; ++cb) {
      int lc = l * 2 + cb;
      const float* src = (cb == 0) ? hin : h;
      dwconv_kernel<<<convG, blk, 0, stream>>>(src, dw_w + (size_t)lc * C * KW,
                                               dw_b + (size_t)lc * C, xbf);
      gemm_mfma<false, false, true><<<gemmC2, blkG, 0, stream>>>(
          xbf, WA + (cb ? SEG_PW1 : SEG_PW0), pw_b + (size_t)lc * C, R0, C, C);
      if (cb == 0)
        ln_kernel<false, true><<<M / 4, blk, 0, stream>>>(
            R0, cln_g + (size_t)lc * C, cln_b + (size_t)lc * C, h, nullptr);
      else  // dual: bf16 copy feeds fused QKV GEMM
        ln_kernel<true, true><<<M / 4, blk, 0, stream>>>(
            R0, cln_g + (size_t)lc * C, cln_b + (size_t)lc * C, h, xbf);
    }
    // ---- attention ----
    gemm_mfma<false, true, false><<<gemmQKV, blkG, 0, stream>>>(
        xbf, WA + SEG_WQ, qkvb, qkvbf, 3 * C, C);
    attn_mfma_kernel<<<attnG, blk, 0, stream>>>(qkvbf, xbf);
    gemm_mfma<false, false, true><<<gemmC2, blkG, 0, stream>>>(
        xbf, WA + SEG_WO, bo + (size_t)l * C, R0, C, C);
    ln_kernel<true, true><<<M / 4, blk, 0, stream>>>(
        R0, aln_g + (size_t)l * C, aln_b + (size_t)l * C, h, fbf);
    // ---- FFN ----
    gemm_mfma<true, true, false><<<gemmH, blkG, 0, stream>>>(
        fbf, WA + SEG_W1, b1 + (size_t)l * HID, hbf, HID, C);
    gemm_mfma<false, false, true><<<gemmC2, blkG, 0, stream>>>(
        hbf, WA + SEG_W2, b2 + (size_t)l * C, R0, C, HID);
    ln_kernel<false, true><<<M / 4, blk, 0, stream>>>(
        R0, fln_g + (size_t)l * C, fln_b + (size_t)l * C, h, nullptr);
  }
}

// Round 8
// 974.193 us; speedup vs baseline: 1.2263x; 1.0035x over previous
//
#include <hip/hip_runtime.h>
#include <hip/hip_bf16.h>

namespace {
constexpr int B = 16, T = 500, C = 512, KW = 7, NH = 8, HD = 64, HID = 2048;
constexpr int M = B * T;             // 8000 rows
constexpr float SCALE = 0.125f;      // 1/sqrt(HD)
constexpr int BTC = B * T * C;       // 4,096,000
// weight arena segment offsets (bf16 element offsets)
constexpr int CC = C * C;                      // 262144
constexpr int SEG_PW0 = 0;
constexpr int SEG_PW1 = CC;
constexpr int SEG_WQ  = 2 * CC;
constexpr int SEG_WK  = 3 * CC;  // contiguous after WQ -> fused QKV GEMM
constexpr int SEG_WV  = 4 * CC;
constexpr int SEG_WO  = 5 * CC;
constexpr int SEG_W1  = 6 * CC;                // 1572864
constexpr int SEG_W2  = 6 * CC + HID * C;     // 2621440
constexpr int SEG_END = 6 * CC + 2 * HID * C; // 3670016
}

typedef short s16x8 __attribute__((ext_vector_type(8)));   // 8 bf16 (4 VGPRs)
typedef float f32x4v __attribute__((ext_vector_type(4)));  // MFMA acc
typedef unsigned short u16x4 __attribute__((ext_vector_type(4)));

__device__ __forceinline__ unsigned int bfrne(float f) {  // f32 -> bf16 RNE
  unsigned int u = __float_as_uint(f);
  return (u + 0x7fffu + ((u >> 16) & 1u)) >> 16;
}
__device__ __forceinline__ unsigned int pack2(float a, float b) {
  return bfrne(a) | (bfrne(b) << 16);
}

// async global->LDS DMA, 16B per lane; lds dst must be wave-uniform base
// (HW writes base + lane*16), global src is per-lane.
__device__ __forceinline__ void gl_lds16(const unsigned short* g,
                                         unsigned short* l) {
  __builtin_amdgcn_global_load_lds(
      (const __attribute__((address_space(1))) void*)g,
      (__attribute__((address_space(3))) void*)l, 16, 0, 0);
}

// -------- per-layer weight convert: 8 tensors -> bf16 arena (1 launch) ------
__global__ __launch_bounds__(256) void cvtw_kernel(
    const float* __restrict__ pw0, const float* __restrict__ pw1,
    const float* __restrict__ wqp, const float* __restrict__ wkp,
    const float* __restrict__ wvp, const float* __restrict__ wop,
    const float* __restrict__ w1p, const float* __restrict__ w2p,
    unsigned short* __restrict__ dst) {
  size_t e = ((size_t)blockIdx.x * 256 + threadIdx.x) * 8;
  const float* src;
  size_t off;
  if      (e < SEG_PW1) { src = pw0; off = e - SEG_PW0; }
  else if (e < SEG_WQ)  { src = pw1; off = e - SEG_PW1; }
  else if (e < SEG_WK)  { src = wqp; off = e - SEG_WQ; }
  else if (e < SEG_WV)  { src = wkp; off = e - SEG_WK; }
  else if (e < SEG_WO)  { src = wvp; off = e - SEG_WV; }
  else if (e < SEG_W1)  { src = wop; off = e - SEG_WO; }
  else if (e < SEG_W2)  { src = w1p; off = e - SEG_W1; }
  else                  { src = w2p; off = e - SEG_W2; }
  float4 a = *(const float4*)(src + off);
  float4 b = *(const float4*)(src + off + 4);
  uint4 o;
  o.x = pack2(a.x, a.y); o.y = pack2(a.z, a.w);
  o.z = pack2(b.x, b.y); o.w = pack2(b.z, b.w);
  *(uint4*)(dst + e) = o;
}

// -------- concat bq|bk|bv (512 each) into one 1536 bias vector --------------
__global__ __launch_bounds__(256) void biascat_kernel(
    const float* __restrict__ bq, const float* __restrict__ bk,
    const float* __restrict__ bv, float* __restrict__ dst) {
  int i = blockIdx.x * 256 + threadIdx.x;  // 0..1535
  float v = (i < 512) ? bq[i] : (i < 1024 ? bk[i - 512] : bv[i - 1024]);
  dst[i] = v;
}

// ---------------- MFMA bf16 GEMM: Y[M,N] = X[M,K] @ W[N,K]^T + bias ---------
// 128x128 tile, BK=32, 8 waves (512 thr) of 32x64 each.
// SPLIT: gridDim.z=2, block ks handles K-half [ks*K/2,(ks+1)*K/2), writes f32
// partial to Yv + ks*M*N; the following LayerNorm sums both partials (free
// reduction). Doubles blocks/CU on the 252-block N=512 launches AND halves
// the serial K chain -> latency-bound time ~halves.
// Staging: global_load_lds width=16, 2 ops/wave/tile, triple-buffered (48KB),
// depth-2 prefetch, counted s_waitcnt vmcnt(2).
// LDS LINEAR [128][32] bf16 (DMA requires); 16B-chunk XOR swizzle applied
// identically on the GLOBAL source and the ds_read offset (both-sides rule):
// phys chunk = logical chunk ^ ((row>>1)&3). Within each 16-lane quad the
// reads cover all 8 bank-groups x2 -> 2-way (free).
// A-frag: lane holds X[m=lane&15][k=quad*8+j]; B-frag: W[n=lane&15][k=...].
// C/D: col=lane&15, row=quad*4+reg.
template <bool RELU, bool YBF, bool SPLIT>
__global__ __launch_bounds__(512) void gemm_mfma(
    const unsigned short* __restrict__ Xb,
    const unsigned short* __restrict__ Wb, const float* __restrict__ bias,
    void* __restrict__ Yv, int N, int K) {
  __shared__ unsigned short As[3][128 * 32];  // 3 x 8KB
  __shared__ unsigned short Bs[3][128 * 32];  // total 48KB
  const int tid = threadIdx.x;
  const int w = tid >> 6, lane = tid & 63;
  const int quad = lane >> 4, r15 = lane & 15;

  const int ks = SPLIT ? blockIdx.z : 0;
  const int K2 = SPLIT ? (K >> 1) : K;
  const int kbase = ks * K2;

  // XCD-aware bijective block swizzle (locality heuristic over x,y only).
  const int gx = gridDim.x;
  const int nwg = gx * gridDim.y;
  const int orig = blockIdx.y * gx + blockIdx.x;
  const int q8 = nwg >> 3, r8 = nwg & 7;
  const int xcd = orig & 7, sidx = orig >> 3;
  const int tile =
      (xcd < r8 ? xcd * (q8 + 1) : r8 * (q8 + 1) + (xcd - r8) * q8) + sidx;
  const int n0 = (tile % gx) * 128;
  const int m0 = (tile / gx) * 128;

  // ---- staging map: 16 DMA ops per tile (1 A-op + 1 B-op per wave) ----
  const int srow = lane >> 2;                          // 0..15
  const int gch = ((lane & 3) ^ ((lane >> 3) & 3)) * 8;  // 16B chunk offset
  const size_t xsrc =
      (size_t)min(m0 + w * 16 + srow, M - 1) * K + kbase + gch;
  const size_t wsrc = (size_t)(n0 + w * 16 + srow) * K + kbase + gch;

  auto issue = [&](int buf, int k0) {
    gl_lds16(Xb + xsrc + k0, &As[buf][w * 512]);
    gl_lds16(Wb + wsrc + k0, &Bs[buf][w * 512]);
  };

  // ---- fragment read offsets (same XOR involution on the read side) ----
  const int wm = w >> 1, wn = w & 1;     // 4 x 2 wave grid
  const int mh = wm * 32, nh = wn * 64;  // wave sub-tile 32M x 64N
  const int c0 = (quad ^ ((r15 >> 1) & 3)) * 8;

  f32x4v acc[2][4];
#pragma unroll
  for (int i = 0; i < 2; ++i)
#pragma unroll
    for (int j = 0; j < 4; ++j) acc[i][j] = {0.f, 0.f, 0.f, 0.f};

  const int nk = K2 / 32;
  issue(0, 0);
  issue(1, 32);
  int cur = 0, nxt = 2;
  for (int c = 0; c < nk; ++c) {
    // tile c (2 oldest ops/wave) done; tile c+1's 2 ops stay in flight
    if (c + 1 < nk)
      asm volatile("s_waitcnt vmcnt(2)" ::: "memory");
    else
      asm volatile("s_waitcnt vmcnt(0)" ::: "memory");
    __builtin_amdgcn_s_barrier();
    __builtin_amdgcn_sched_barrier(0);
    if (c + 2 < nk) issue(nxt, (c + 2) * 32);
    const unsigned short* Ac = As[cur];
    const unsigned short* Bc = Bs[cur];
    s16x8 af[2], bg[4];
#pragma unroll
    for (int im = 0; im < 2; ++im)
      af[im] = *(const s16x8*)&Ac[(mh + im * 16 + r15) * 32 + c0];
#pragma unroll
    for (int in = 0; in < 4; ++in)
      bg[in] = *(const s16x8*)&Bc[(nh + in * 16 + r15) * 32 + c0];
#pragma unroll
    for (int in = 0; in < 4; ++in)
#pragma unroll
      for (int im = 0; im < 2; ++im)
        acc[im][in] = __builtin_amdgcn_mfma_f32_16x16x32_bf16(
            af[im], bg[in], acc[im][in], 0, 0, 0);
    cur = (cur == 2) ? 0 : cur + 1;
    nxt = (nxt == 2) ? 0 : nxt + 1;
  }
  // epilogue
  float* Yf = (float*)Yv + (SPLIT ? (size_t)ks * M * N : 0);
#pragma unroll
  for (int in = 0; in < 4; ++in) {
    int col = n0 + nh + in * 16 + r15;
    float bv = bias[col];
    if (SPLIT && ks) bv = 0.f;  // bias added once (ks=0 partial)
#pragma unroll
    for (int im = 0; im < 2; ++im) {
      int rowb = m0 + mh + im * 16 + quad * 4;
#pragma unroll
      for (int r = 0; r < 4; ++r) {
        int row = rowb + r;
        if (row < M) {
          float v = acc[im][in][r] + bv;
          if (RELU) v = fmaxf(v, 0.f);
          if (YBF)
            ((unsigned short*)Yv)[(size_t)row * N + col] =
                (unsigned short)bfrne(v);
          else
            Yf[(size_t)row * N + col] = v;
        }
      }
    }
  }
}

// ------- depthwise conv (K=7, pad 3) along T, (B,T,C), bf16 out, 2 ch/thread
__global__ __launch_bounds__(256) void dwconv_kernel(
    const float* __restrict__ X, const float* __restrict__ W,
    const float* __restrict__ bias, unsigned short* __restrict__ Y) {
  int gid = blockIdx.x * 256 + threadIdx.x;  // 0 .. T*C/2-1
  int b = blockIdx.y;
  int e = gid * 2;
  int t = e >> 9;
  int c = e & 511;  // even
  float acc0 = bias[c], acc1 = bias[c + 1];
  size_t base = (size_t)b * T * C;
#pragma unroll
  for (int k = 0; k < KW; ++k) {
    int tt = t + k - 3;
    if (tt >= 0 && tt < T) {
      float2 xv = *(const float2*)&X[base + (size_t)tt * C + c];
      acc0 += xv.x * W[c * KW + k];
      acc1 += xv.y * W[(c + 1) * KW + k];
    }
  }
  *(unsigned int*)&Y[base + e] = pack2(acc0, acc1);
}

// --------- row LayerNorm over C=512, one wave/row, vectorized --------------
// SUM2: input = X[row] + X[row + BTC] (sums the two split-K GEMM partials --
// the free reduction). DUAL: also emit bf16 copy.
template <bool DUAL, bool SUM2>
__global__ __launch_bounds__(256) void ln_kernel(
    const float* __restrict__ X, const float* __restrict__ g,
    const float* __restrict__ bta, float* __restrict__ Y,
    unsigned short* __restrict__ Yb) {
  int row = blockIdx.x * 4 + (threadIdx.x >> 6);
  int lane = threadIdx.x & 63;
  const float* x = X + (size_t)row * C + lane * 8;
  float4 a = *(const float4*)x;
  float4 b2 = *(const float4*)(x + 4);
  float v[8] = {a.x, a.y, a.z, a.w, b2.x, b2.y, b2.z, b2.w};
  if (SUM2) {
    const float* x2 = x + (size_t)BTC;
    float4 a2 = *(const float4*)x2;
    float4 b3 = *(const float4*)(x2 + 4);
    v[0] += a2.x; v[1] += a2.y; v[2] += a2.z; v[3] += a2.w;
    v[4] += b3.x; v[5] += b3.y; v[6] += b3.z; v[7] += b3.w;
  }
  float s = 0.f, ss = 0.f;
#pragma unroll
  for (int i = 0; i < 8; ++i) {
    s += v[i];
    ss += v[i] * v[i];
  }
#pragma unroll
  for (int off = 32; off; off >>= 1) {
    s += __shfl_xor(s, off);
    ss += __shfl_xor(ss, off);
  }
  float mean = s * (1.f / C);
  float var = ss * (1.f / C) - mean * mean;
  var = fmaxf(var, 0.f);
  float rstd = rsqrtf(var + 1e-5f);
  float4 g0 = *(const float4*)(g + lane * 8);
  float4 g1 = *(const float4*)(g + lane * 8 + 4);
  float4 be0 = *(const float4*)(bta + lane * 8);
  float4 be1 = *(const float4*)(bta + lane * 8 + 4);
  float gg[8] = {g0.x, g0.y, g0.z, g0.w, g1.x, g1.y, g1.z, g1.w};
  float bb[8] = {be0.x, be0.y, be0.z, be0.w, be1.x, be1.y, be1.z, be1.w};
  float o[8];
#pragma unroll
  for (int i = 0; i < 8; ++i) o[i] = (v[i] - mean) * rstd * gg[i] + bb[i];
  float* y = Y + (size_t)row * C + lane * 8;
  float4 w0 = {o[0], o[1], o[2], o[3]};
  float4 w1 = {o[4], o[5], o[6], o[7]};
  *(float4*)y = w0;
  *(float4*)(y + 4) = w1;
  if (DUAL) {
    uint4 ob;
    ob.x = pack2(o[0], o[1]); ob.y = pack2(o[2], o[3]);
    ob.z = pack2(o[4], o[5]); ob.w = pack2(o[6], o[7]);
    *(uint4*)(Yb + (size_t)row * C + lane * 8) = ob;
  }
}

// ---------- causal flash attention, MFMA bf16, bf16 in (QKV fused) / out ----
// QKV: [M, 1536] bf16 (Q|K|V each 512 cols). Block = (128-q tile, head,
// batch), 512 threads / 8 waves; wave w owns q rows [q0+16w, q0+16w+16).
// Key tiles of 64, K/V prefetched into registers (next tile's global loads
// issued before compute -> latency hidden under QK/softmax/PV).
// Longest-first: qt = gridDim.x-1-blockIdx.x (work ~ qt+1).
// K staged [key][d] linear (LDK=72: reads+writes conflict-free, verified by
// bank enumeration). V staged transposed [d][key] with 16B-chunk XOR swizzle
// pc = kc ^ ((d>>2)&7) applied on BOTH write and read -> writes 2-way (free),
// reads exactly 8 lanes/bank-window (optimal). Waves whose whole q-range is
// below key0 skip compute (their rows never see keys > q... all keys <= q).
__global__ __launch_bounds__(512) void attn_mfma_kernel(
    const unsigned short* __restrict__ QKV, unsigned short* __restrict__ Yb) {
  constexpr int QS = 3 * C;  // 1536
  constexpr int LDK = 72;
  __shared__ __align__(16) unsigned short Ks[64 * LDK];     // [key][d]
  __shared__ __align__(16) unsigned short Vt[64 * LDK];     // [d][key] swz
  __shared__ __align__(16) unsigned short Ps[8][16 * LDK];  // per-wave [q][key]
  const int tid = threadIdx.x;
  const int lane = tid & 63, w = tid >> 6;
  const int quad = lane >> 4, r15 = lane & 15;
  const int qt = (gridDim.x - 1) - blockIdx.x;  // longest-first
  const int hh = blockIdx.y, b = blockIdx.z;
  const int q0 = qt * 128;
  const size_t hbase = (size_t)hh * HD;
  const size_t bT = (size_t)b * T;

  // Q A-frags: lane holds Q[q0+16w+r15][ks*32+quad*8 .. +8)
  s16x8 qa[2];
  {
    int qr = min(q0 + w * 16 + r15, T - 1);
    const unsigned short* qp = QKV + (bT + qr) * QS + hbase;
    qa[0] = *(const s16x8*)(qp + quad * 8);
    qa[1] = *(const s16x8*)(qp + 32 + quad * 8);
  }

  f32x4v oacc[4];
  float mm[4], ll[4];
#pragma unroll
  for (int i = 0; i < 4; ++i) {
    oacc[i] = {0.f, 0.f, 0.f, 0.f};
    mm[i] = -1e30f;
    ll[i] = 0.f;
  }

  // staging maps (512 threads)
  const int krow = tid >> 3, kd = (tid & 7) * 8;  // K: one 16B chunk/thread
  const int vd4 = (tid & 15) * 4;                 // V: 4 d-rows x 2 keys
  const int vk2 = (tid >> 4) * 2;
  const int vsub = vk2 & 7;                       // elem sub within 16B chunk
  const int vkc = vk2 >> 3;                       // logical key chunk
  const int pc8 = (vkc ^ (tid & 7)) * 8;          // f(row)=(row>>2)&7 = tid&7

  auto loadK = [&](int key0, uint4& kreg) {
    int key = key0 + krow;
    if (key < T)
      kreg = *(const uint4*)(QKV + (bT + key) * QS + C + hbase + kd);
    else
      kreg = (uint4){0u, 0u, 0u, 0u};
  };
  auto loadV = [&](int key0, u16x4* vreg) {
#pragma unroll
    for (int j = 0; j < 2; ++j) {
      int key = key0 + vk2 + j;
      if (key < T)
        vreg[j] = *(const u16x4*)(QKV + (bT + key) * QS + 2 * C + hbase + vd4);
      else
        vreg[j] = (u16x4){0, 0, 0, 0};
    }
  };
  auto storeKV = [&](uint4 kreg, const u16x4* vreg) {
    *(uint4*)&Ks[krow * LDK + kd] = kreg;
#pragma unroll
    for (int i = 0; i < 4; ++i) {
      unsigned int o = (unsigned int)(unsigned short)vreg[0][i] |
                       ((unsigned int)(unsigned short)vreg[1][i] << 16);
      *(unsigned int*)&Vt[(vd4 + i) * LDK + pc8 + vsub] = o;
    }
  };

  const int kend = min(q0 + 127, T - 1);
  const int myqmax = q0 + w * 16 + 15;

  uint4 kr;
  u16x4 vr[2];
  loadK(0, kr);
  loadV(0, vr);
  for (int key0 = 0; key0 <= kend; key0 += 64) {
    __syncthreads();  // previous tile's LDS reads done
    storeKV(kr, vr);
    const bool more = (key0 + 64 <= kend);
    uint4 nk;
    u16x4 nv[2];
    if (more) {  // prefetch next tile; latency hides under compute below
      loadK(key0 + 64, nk);
      loadV(key0 + 64, nv);
    }
    __syncthreads();
    if (key0 <= myqmax) {  // wave-level causal skip
      // ---- S = Q K^T (16 q x 64 keys) ----
      f32x4v sa[4];
      __builtin_amdgcn_s_setprio(1);
#pragma unroll
      for (int nt = 0; nt < 4; ++nt) {
        s16x8 kb0 = *(const s16x8*)&Ks[(nt * 16 + r15) * LDK + quad * 8];
        s16x8 kb1 = *(const s16x8*)&Ks[(nt * 16 + r15) * LDK + 32 + quad * 8];
        f32x4v z = {0.f, 0.f, 0.f, 0.f};
        z = __builtin_amdgcn_mfma_f32_16x16x32_bf16(qa[0], kb0, z, 0, 0, 0);
        z = __builtin_amdgcn_mfma_f32_16x16x32_bf16(qa[1], kb1, z, 0, 0, 0);
        sa[nt] = z;
      }
      __builtin_amdgcn_s_setprio(0);
      const bool needmask = (key0 + 63 > q0 + w * 16);

      // ---- online softmax; C-layout row = quad*4+r, col = nt*16+r15 ----
#pragma unroll
      for (int r = 0; r < 4; ++r) {
        int q = q0 + w * 16 + quad * 4 + r;
        if (q >= T) continue;  // never written out; Ps row unused rows only
        float sv[4];
#pragma unroll
        for (int nt = 0; nt < 4; ++nt) {
          sv[nt] = sa[nt][r] * SCALE;
          if (needmask && (key0 + nt * 16 + r15 > q)) sv[nt] = -1e30f;
        }
        float mx = fmaxf(fmaxf(sv[0], sv[1]), fmaxf(sv[2], sv[3]));
        mx = fmaxf(mx, __shfl_xor(mx, 8));
        mx = fmaxf(mx, __shfl_xor(mx, 4));
        mx = fmaxf(mx, __shfl_xor(mx, 2));
        mx = fmaxf(mx, __shfl_xor(mx, 1));
        float mnew = fmaxf(mm[r], mx);
        float alpha = __expf(mm[r] - mnew);
        float ps = 0.f;
#pragma unroll
        for (int nt = 0; nt < 4; ++nt) {
          float p = __expf(sv[nt] - mnew);
          ps += p;
          Ps[w][(quad * 4 + r) * LDK + nt * 16 + r15] =
              (unsigned short)bfrne(p);
        }
        ps += __shfl_xor(ps, 8);
        ps += __shfl_xor(ps, 4);
        ps += __shfl_xor(ps, 2);
        ps += __shfl_xor(ps, 1);
        ll[r] = ll[r] * alpha + ps;
        mm[r] = mnew;
#pragma unroll
        for (int dt = 0; dt < 4; ++dt) oacc[dt][r] *= alpha;
      }
      // per-wave LDS round-trip: drain this wave's Ps writes before reading
      asm volatile("s_waitcnt lgkmcnt(0)" ::: "memory");
      __builtin_amdgcn_sched_barrier(0);

      // ---- O += P @ V (Vt read with the same chunk-XOR swizzle) ----
      s16x8 pa0 = *(const s16x8*)&Ps[w][r15 * LDK + quad * 8];
      s16x8 pa1 = *(const s16x8*)&Ps[w][r15 * LDK + 32 + quad * 8];
      __builtin_amdgcn_s_setprio(1);
#pragma unroll
      for (int dt = 0; dt < 4; ++dt) {
        const int rd = dt * 16 + r15;
        const int fr = (rd >> 2) & 7;
        s16x8 vb0 = *(const s16x8*)&Vt[rd * LDK + (quad ^ fr) * 8];
        s16x8 vb1 = *(const s16x8*)&Vt[rd * LDK + ((quad + 4) ^ fr) * 8];
        oacc[dt] = __builtin_amdgcn_mfma_f32_16x16x32_bf16(pa0, vb0,
                                                           oacc[dt], 0, 0, 0);
        oacc[dt] = __builtin_amdgcn_mfma_f32_16x16x32_bf16(pa1, vb1,
                                                           oacc[dt], 0, 0, 0);
      }
      __builtin_amdgcn_s_setprio(0);
    }
    if (more) {
      kr = nk;
      vr[0] = nv[0];
      vr[1] = nv[1];
    }
  }

  // ---- write out bf16 (row = quad*4+r, col = dt*16+r15) ----
#pragma unroll
  for (int r = 0; r < 4; ++r) {
    int q = q0 + w * 16 + quad * 4 + r;
    if (q < T) {
      float inv = 1.f / ll[r];
      unsigned short* yp = Yb + (bT + q) * C + hbase;
#pragma unroll
      for (int dt = 0; dt < 4; ++dt)
        yp[dt * 16 + r15] = (unsigned short)bfrne(oacc[dt][r] * inv);
    }
  }
}

extern "C" void kernel_launch(void* const* d_in, const int* in_sizes, int n_in,
                              void* d_out, int out_size, void* d_ws,
                              size_t ws_size, hipStream_t stream) {
  const float* x     = (const float*)d_in[0];
  const float* dw_w  = (const float*)d_in[1];
  const float* dw_b  = (const float*)d_in[2];
  const float* pw_w  = (const float*)d_in[3];
  const float* pw_b  = (const float*)d_in[4];
  const float* cln_g = (const float*)d_in[5];
  const float* cln_b = (const float*)d_in[6];
  const float* wq    = (const float*)d_in[7];
  const float* bq    = (const float*)d_in[8];
  const float* wk    = (const float*)d_in[9];
  const float* bk    = (const float*)d_in[10];
  const float* wv    = (const float*)d_in[11];
  const float* bv    = (const float*)d_in[12];
  const float* wo    = (const float*)d_in[13];
  const float* bo    = (const float*)d_in[14];
  const float* aln_g = (const float*)d_in[15];
  const float* aln_b = (const float*)d_in[16];
  const float* w1    = (const float*)d_in[17];
  const float* b1    = (const float*)d_in[18];
  const float* w2    = (const float*)d_in[19];
  const float* b2    = (const float*)d_in[20];
  const float* fln_g = (const float*)d_in[21];
  const float* fln_b = (const float*)d_in[22];

  float* ws = (float*)d_ws;
  float* A  = ws;                      // qkv bias / ffn1-out bf16 (spans A,Bf)
  float* Bf = ws + (size_t)BTC;        // bf16 activation slot
  float* R0 = ws + (size_t)2 * BTC;    // partial0 / QKV bf16 (spans into R1)
  float* R1 = ws + (size_t)3 * BTC;    // partial1
  float* R2 = ws + (size_t)4 * BTC;    // ffn1 input bf16
  unsigned short* WA = (unsigned short*)(ws + (size_t)5 * BTC);  // 7.4 MB
  float* out = (float*)d_out;          // 3 layer outputs, f32

  unsigned short* xbf   = (unsigned short*)Bf;   // conv-GEMM in / QKV in / attn out
  unsigned short* qkvbf = (unsigned short*)R0;   // QKV GEMM out [M,1536] bf16
  unsigned short* fbf   = (unsigned short*)R2;   // ffn1 input bf16
  unsigned short* hbf   = (unsigned short*)A;    // ffn1 output bf16 (spans A,Bf)
  float* qkvb = A;                               // 1536-wide concat bias

  dim3 blk(256);
  dim3 blkG(512);                    // 8-wave GEMM blocks
  dim3 gemmC2(C / 128, 63, 2);       // N=512, split-K=2 -> 504 blocks
  dim3 gemmQKV(3 * C / 128, 63);     // N=1536, 756 blocks
  dim3 gemmH(HID / 128, 63);         // N=2048, 1008 blocks
  dim3 convG(T * C / 512, B);        // 2 channels/thread
  dim3 attnG((T + 127) / 128, NH, B);  // 512 blocks, 512 thr
  int cvtwB = SEG_END / 2048;        // 1792 blocks

  for (int l = 0; l < 3; ++l) {
    float* h = out + (size_t)l * BTC;
    const float* hin = (l == 0) ? x : out + (size_t)(l - 1) * BTC;
    cvtw_kernel<<<cvtwB, blk, 0, stream>>>(
        pw_w + (size_t)(2 * l) * CC, pw_w + (size_t)(2 * l + 1) * CC,
        wq + (size_t)l * CC, wk + (size_t)l * CC, wv + (size_t)l * CC,
        wo + (size_t)l * CC, w1 + (size_t)l * HID * C,
        w2 + (size_t)l * C * HID, WA);
    biascat_kernel<<<6, blk, 0, stream>>>(bq + (size_t)l * C,
                                          bk + (size_t)l * C,
                                          bv + (size_t)l * C, qkvb);
    // ---- 2 conv blocks (pointwise GEMM split-K=2, LN sums partials) ----
    for (int cb = 0; cb < 2; ++cb) {
      int lc = l * 2 + cb;
      const float* src = (cb == 0) ? hin : h;
      dwconv_kernel<<<convG, blk, 0, stream>>>(src, dw_w + (size_t)lc * C * KW,
                                               dw_b + (size_t)lc * C, xbf);
      gemm_mfma<false, false, true><<<gemmC2, blkG, 0, stream>>>(
          xbf, WA + (cb ? SEG_PW1 : SEG_PW0), pw_b + (size_t)lc * C, R0, C, C);
      if (cb == 0)
        ln_kernel<false, true><<<M / 4, blk, 0, stream>>>(
            R0, cln_g + (size_t)lc * C, cln_b + (size_t)lc * C, h, nullptr);
      else  // dual: bf16 copy feeds fused QKV GEMM
        ln_kernel<true, true><<<M / 4, blk, 0, stream>>>(
            R0, cln_g + (size_t)lc * C, cln_b + (size_t)lc * C, h, xbf);
    }
    // ---- attention ----
    gemm_mfma<false, true, false><<<gemmQKV, blkG, 0, stream>>>(
        xbf, WA + SEG_WQ, qkvb, qkvbf, 3 * C, C);
    attn_mfma_kernel<<<attnG, blkG, 0, stream>>>(qkvbf, xbf);
    gemm_mfma<false, false, true><<<gemmC2, blkG, 0, stream>>>(
        xbf, WA + SEG_WO, bo + (size_t)l * C, R0, C, C);
    ln_kernel<true, true><<<M / 4, blk, 0, stream>>>(
        R0, aln_g + (size_t)l * C, aln_b + (size_t)l * C, h, fbf);
    // ---- FFN ----
    gemm_mfma<true, true, false><<<gemmH, blkG, 0, stream>>>(
        fbf, WA + SEG_W1, b1 + (size_t)l * HID, hbf, HID, C);
    gemm_mfma<false, false, true><<<gemmC2, blkG, 0, stream>>>(
        hbf, WA + SEG_W2, b2 + (size_t)l * C, R0, C, HID);
    ln_kernel<false, true><<<M / 4, blk, 0, stream>>>(
        R0, fln_g + (size_t)l * C, fln_b + (size_t)l * C, h, nullptr);
  }
}